// Round 11
// baseline (870.201 us; speedup 1.0000x reference)
//
#include <hip/hip_runtime.h>

typedef unsigned short u16;
typedef unsigned int u32;
typedef unsigned long long u64;
typedef __attribute__((ext_vector_type(4))) unsigned short u16x4;
typedef __attribute__((ext_vector_type(8))) unsigned short u16x8;
typedef __attribute__((ext_vector_type(4))) float f32x4;
typedef __attribute__((ext_vector_type(8))) __bf16 bf16x8;

#define DD 2048
#define TT 2048
#define FSH 11008

__device__ __forceinline__ float bf2f(u16 u) {
  union { u32 i; float f; } v; v.i = ((u32)u) << 16; return v.f;
}
__device__ __forceinline__ u16 f2bf(float f) {
  union { float f; u32 i; } v; v.f = f;
  u32 r = v.i + 0x7fffu + ((v.i >> 16) & 1u);
  return (u16)(r >> 16);
}
__device__ __forceinline__ void gld16(const void* g, void* l) {
  __builtin_amdgcn_global_load_lds((const __attribute__((address_space(1))) void*)g,
                                   (__attribute__((address_space(3))) void*)l, 16, 0, 0);
}

#define MFMA16(d, a, b) d = __builtin_amdgcn_mfma_f32_16x16x32_bf16(a, b, d, 0, 0, 0)

// ---------------- 64x64 tile transpose helper (256 threads, XOR-swizzled LDS) ----------
__device__ __forceinline__ void ttile(const float* __restrict__ Wm, u16* __restrict__ Wtm,
                                      int R, int C, int n0, int k0, u16* tile, int t) {
#pragma unroll
  for (int p = 0; p < 4; ++p) {
    const int kk = (t >> 4) + p * 16;
    const int nn = (t & 15) * 4;
    float4 v = *(const float4*)(Wm + (size_t)(k0 + kk) * C + n0 + nn);
    const float vv[4] = {v.x, v.y, v.z, v.w};
#pragma unroll
    for (int j = 0; j < 4; ++j) {
      const int n = nn + j;
      tile[n * 80 + (kk ^ (((n >> 2) & 7) << 3))] = f2bf(vv[j]);
    }
  }
  __syncthreads();
#pragma unroll
  for (int p = 0; p < 2; ++p) {
    const int n = (t >> 3) + p * 32;
    const int c = t & 7;
    u16x8 v = *(const u16x8*)(tile + n * 80 + ((c * 8) ^ (((n >> 2) & 7) << 3)));
    *(u16x8*)(Wtm + (size_t)(n0 + n) * R + k0 + c * 8) = v;
  }
}

// ---------------- RMSNorm (f32->bf16) + fused wq/wk/wv transpose (tail blocks) ----------
__global__ __launch_bounds__(256) void rmsnorm_k(const float* __restrict__ x,
                                                 const float* __restrict__ w,
                                                 u16* __restrict__ out,
                                                 const float* __restrict__ wq,
                                                 const float* __restrict__ wk,
                                                 const float* __restrict__ wv,
                                                 u16* __restrict__ WTQ) {
  __shared__ u16 tile[64 * 80];
  __shared__ float red[4];
  const int t = threadIdx.x;
  if ((int)blockIdx.x >= TT) {
    const int bi = blockIdx.x - TT;   // [0,192): 1536 tiles total
#pragma unroll 1
    for (int i = 0; i < 8; ++i) {
      const int ti = bi * 8 + i;
      if (ti < 1024) {
        ttile(wq, WTQ, 2048, 2048, (ti & 31) * 64, (ti >> 5) * 64, tile, t);
      } else if (ti < 1280) {
        const int r = ti - 1024;
        ttile(wk, WTQ + (size_t)2048 * 2048, 2048, 512, (r & 7) * 64, (r >> 3) * 64, tile, t);
      } else {
        const int r = ti - 1280;
        ttile(wv, WTQ + (size_t)2560 * 2048, 2048, 512, (r & 7) * 64, (r >> 3) * 64, tile, t);
      }
      __syncthreads();
    }
    return;
  }
  const float* xr = x + (size_t)blockIdx.x * DD;
  float4 a = *(const float4*)(xr + t * 8);
  float4 b = *(const float4*)(xr + t * 8 + 4);
  float ss = a.x*a.x + a.y*a.y + a.z*a.z + a.w*a.w
           + b.x*b.x + b.y*b.y + b.z*b.z + b.w*b.w;
#pragma unroll
  for (int m = 1; m < 64; m <<= 1) ss += __shfl_xor(ss, m);
  if ((t & 63) == 0) red[t >> 6] = ss;
  __syncthreads();
  float sc = rsqrtf((red[0] + red[1] + red[2] + red[3]) * (1.f / DD) + 1e-6f);
  float4 wa = *(const float4*)(w + t * 8);
  float4 wb = *(const float4*)(w + t * 8 + 4);
  u16x8 o;
  o[0] = f2bf(a.x * sc * wa.x); o[1] = f2bf(a.y * sc * wa.y);
  o[2] = f2bf(a.z * sc * wa.z); o[3] = f2bf(a.w * sc * wa.w);
  o[4] = f2bf(b.x * sc * wb.x); o[5] = f2bf(b.y * sc * wb.y);
  o[6] = f2bf(b.z * sc * wb.z); o[7] = f2bf(b.w * sc * wb.w);
  *(u16x8*)(out + (size_t)blockIdx.x * DD + t * 8) = o;
}

// ---------------- GEMM8: 256^2, 8-wave, 8-phase ----------------
// EPI: 2=bf16, 3=bf16 silu(aux)*acc, 4=bf16 slotw[row]*acc, 10=bf16 parts, 11=f32 parts
template <int EPI, bool SPLITK, bool EXPERT>
__global__ __launch_bounds__(512, 2) void gemm8(
    const u16* __restrict__ A, const u16* __restrict__ Bt, void* __restrict__ Cp,
    const u16* __restrict__ aux, const float* __restrict__ slotw,
    const int* __restrict__ tiletab, int M, int N, int K, int Kc) {
  __shared__ char lds[131072];
  const int t = threadIdx.x, w = t >> 6, l = t & 63;
  int m0, n0;
  if constexpr (EXPERT) {
    const int ntil = tiletab[0];
    if ((int)blockIdx.y >= ntil) return;
    const int e = tiletab[1 + blockIdx.y * 2];
    m0 = tiletab[2 + blockIdx.y * 2];
    n0 = blockIdx.x * 256;
    Bt += (size_t)e * N * K;
  } else {
    const int gx = gridDim.x, gy = gridDim.y;
    const int nwg = gx * gy;          // % 8 == 0
    int wg = blockIdx.y * gx + blockIdx.x;
    wg = (wg & 7) * (nwg >> 3) + (wg >> 3);   // XCD swizzle (bijective)
    m0 = (wg % gy) * 256;             // n-major
    n0 = (wg / gy) * 256;
  }
  int kbase = 0, KC = K;
  if constexpr (SPLITK) {
    kbase = blockIdx.z * Kc;
    const int rem = K - kbase;
    KC = rem < Kc ? rem : Kc;
  }
  const int ktiles = KC >> 6;
  const int wm = w >> 2, wn = w & 3;
  const int l15 = l & 15, l4 = l >> 4;
  const int sro = l >> 3, sc = l & 7;

  const u16* sgp[2][2][2];
  u32 sdo[2][2][2];
#pragma unroll
  for (int isB = 0; isB < 2; ++isB)
#pragma unroll
    for (int h = 0; h < 2; ++h)
#pragma unroll
      for (int i = 0; i < 2; ++i) {
        const int q = i * 8 + w;
        const int r0 = isB ? (((q >> 2) << 6) + h * 32 + (q & 3) * 8)
                           : (((q & 8) << 4) + h * 64 + (q & 7) * 8);
        const int r = r0 + sro;
        const int cl = sc ^ (r & 7);
        const u16* base = isB ? (Bt + (size_t)(n0 + r) * K) : (A + (size_t)(m0 + r) * K);
        sgp[isB][h][i] = base + kbase + cl * 8;
        sdo[isB][h][i] = (u32)(isB * 32768 + r0 * 128);
      }
  auto stage = [&](int b, int isB, int h, int kt) {
    const int kk = kt < ktiles ? kt : ktiles - 1;
#pragma unroll
    for (int i = 0; i < 2; ++i)
      gld16(sgp[isB][h][i] + kk * 64, lds + b * 65536 + sdo[isB][h][i]);
  };
  auto ldA = [&](int b, int mi, int ks) {
    const int row = wm * 128 + mi * 16 + l15;
    const int ch = (ks * 4 + l4) ^ (row & 7);
    return *(const bf16x8*)(lds + b * 65536 + row * 128 + ch * 16);
  };
  auto ldB = [&](int b, int ni, int ks) {
    const int row = wn * 64 + ni * 16 + l15;
    const int ch = (ks * 4 + l4) ^ (row & 7);
    return *(const bf16x8*)(lds + b * 65536 + 32768 + row * 128 + ch * 16);
  };

  f32x4 acc[8][4] = {};
  bf16x8 aR[4][2], b0[2][2], b1[2][2];

  stage(0, 0, 0, 0); stage(0, 1, 0, 0); stage(0, 1, 1, 0); stage(0, 0, 1, 0);
  stage(1, 0, 0, 1); stage(1, 1, 1, 1); stage(1, 0, 1, 1);
  asm volatile("s_waitcnt vmcnt(6)" ::: "memory");
  __builtin_amdgcn_s_barrier();

  for (int kt = 0; kt < ktiles; kt += 2) {
#pragma unroll
    for (int mi = 0; mi < 4; ++mi) { aR[mi][0] = ldA(0, mi, 0); aR[mi][1] = ldA(0, mi, 1); }
#pragma unroll
    for (int ni = 0; ni < 2; ++ni) { b0[ni][0] = ldB(0, ni, 0); b0[ni][1] = ldB(0, ni, 1); }
    stage(1, 1, 0, kt + 1);
    __builtin_amdgcn_s_barrier();
    asm volatile("s_waitcnt lgkmcnt(0)" ::: "memory");
    __builtin_amdgcn_s_setprio(1);
#pragma unroll
    for (int mi = 0; mi < 4; ++mi)
#pragma unroll
      for (int ni = 0; ni < 2; ++ni) {
        MFMA16(acc[mi][ni], aR[mi][0], b0[ni][0]);
        MFMA16(acc[mi][ni], aR[mi][1], b0[ni][1]);
      }
    __builtin_amdgcn_s_setprio(0);
    __builtin_amdgcn_s_barrier();
#pragma unroll
    for (int ni = 0; ni < 2; ++ni) { b1[ni][0] = ldB(0, ni + 2, 0); b1[ni][1] = ldB(0, ni + 2, 1); }
    stage(0, 0, 0, kt + 2);
    __builtin_amdgcn_s_barrier();
    asm volatile("s_waitcnt lgkmcnt(0)" ::: "memory");
    __builtin_amdgcn_s_setprio(1);
#pragma unroll
    for (int mi = 0; mi < 4; ++mi)
#pragma unroll
      for (int ni = 0; ni < 2; ++ni) {
        MFMA16(acc[mi][ni + 2], aR[mi][0], b1[ni][0]);
        MFMA16(acc[mi][ni + 2], aR[mi][1], b1[ni][1]);
      }
    __builtin_amdgcn_s_setprio(0);
    __builtin_amdgcn_s_barrier();
#pragma unroll
    for (int mi = 0; mi < 4; ++mi) { aR[mi][0] = ldA(0, mi + 4, 0); aR[mi][1] = ldA(0, mi + 4, 1); }
    stage(0, 1, 1, kt + 2);
    __builtin_amdgcn_s_barrier();
    asm volatile("s_waitcnt lgkmcnt(0)" ::: "memory");
    __builtin_amdgcn_s_setprio(1);
#pragma unroll
    for (int mi = 0; mi < 4; ++mi)
#pragma unroll
      for (int ni = 0; ni < 2; ++ni) {
        MFMA16(acc[mi + 4][ni + 2], aR[mi][0], b1[ni][0]);
        MFMA16(acc[mi + 4][ni + 2], aR[mi][1], b1[ni][1]);
      }
    __builtin_amdgcn_s_setprio(0);
    __builtin_amdgcn_s_barrier();
    stage(0, 0, 1, kt + 2);
    __builtin_amdgcn_s_barrier();
    __builtin_amdgcn_s_setprio(1);
#pragma unroll
    for (int mi = 0; mi < 4; ++mi)
#pragma unroll
      for (int ni = 0; ni < 2; ++ni) {
        MFMA16(acc[mi + 4][ni], aR[mi][0], b0[ni][0]);
        MFMA16(acc[mi + 4][ni], aR[mi][1], b0[ni][1]);
      }
    __builtin_amdgcn_s_setprio(0);
    asm volatile("s_waitcnt vmcnt(6)" ::: "memory");
    __builtin_amdgcn_s_barrier();
#pragma unroll
    for (int mi = 0; mi < 4; ++mi) { aR[mi][0] = ldA(1, mi, 0); aR[mi][1] = ldA(1, mi, 1); }
#pragma unroll
    for (int ni = 0; ni < 2; ++ni) { b0[ni][0] = ldB(1, ni, 0); b0[ni][1] = ldB(1, ni, 1); }
    stage(0, 1, 0, kt + 2);
    __builtin_amdgcn_s_barrier();
    asm volatile("s_waitcnt lgkmcnt(0)" ::: "memory");
    __builtin_amdgcn_s_setprio(1);
#pragma unroll
    for (int mi = 0; mi < 4; ++mi)
#pragma unroll
      for (int ni = 0; ni < 2; ++ni) {
        MFMA16(acc[mi][ni], aR[mi][0], b0[ni][0]);
        MFMA16(acc[mi][ni], aR[mi][1], b0[ni][1]);
      }
    __builtin_amdgcn_s_setprio(0);
    __builtin_amdgcn_s_barrier();
#pragma unroll
    for (int ni = 0; ni < 2; ++ni) { b1[ni][0] = ldB(1, ni + 2, 0); b1[ni][1] = ldB(1, ni + 2, 1); }
    stage(1, 0, 0, kt + 3);
    __builtin_amdgcn_s_barrier();
    asm volatile("s_waitcnt lgkmcnt(0)" ::: "memory");
    __builtin_amdgcn_s_setprio(1);
#pragma unroll
    for (int mi = 0; mi < 4; ++mi)
#pragma unroll
      for (int ni = 0; ni < 2; ++ni) {
        MFMA16(acc[mi][ni + 2], aR[mi][0], b1[ni][0]);
        MFMA16(acc[mi][ni + 2], aR[mi][1], b1[ni][1]);
      }
    __builtin_amdgcn_s_setprio(0);
    __builtin_amdgcn_s_barrier();
#pragma unroll
    for (int mi = 0; mi < 4; ++mi) { aR[mi][0] = ldA(1, mi + 4, 0); aR[mi][1] = ldA(1, mi + 4, 1); }
    stage(1, 1, 1, kt + 3);
    __builtin_amdgcn_s_barrier();
    asm volatile("s_waitcnt lgkmcnt(0)" ::: "memory");
    __builtin_amdgcn_s_setprio(1);
#pragma unroll
    for (int mi = 0; mi < 4; ++mi)
#pragma unroll
      for (int ni = 0; ni < 2; ++ni) {
        MFMA16(acc[mi + 4][ni + 2], aR[mi][0], b1[ni][0]);
        MFMA16(acc[mi + 4][ni + 2], aR[mi][1], b1[ni][1]);
      }
    __builtin_amdgcn_s_setprio(0);
    __builtin_amdgcn_s_barrier();
    stage(1, 0, 1, kt + 3);
    __builtin_amdgcn_s_barrier();
    __builtin_amdgcn_s_setprio(1);
#pragma unroll
    for (int mi = 0; mi < 4; ++mi)
#pragma unroll
      for (int ni = 0; ni < 2; ++ni) {
        MFMA16(acc[mi + 4][ni], aR[mi][0], b0[ni][0]);
        MFMA16(acc[mi + 4][ni], aR[mi][1], b0[ni][1]);
      }
    __builtin_amdgcn_s_setprio(0);
    asm volatile("s_waitcnt vmcnt(6)" ::: "memory");
    __builtin_amdgcn_s_barrier();
  }

  u16* C16 = (u16*)Cp;
  float* Cf = (float*)Cp;
  if constexpr (EPI == 10) C16 += (size_t)blockIdx.z * ((size_t)M * N);
  if constexpr (EPI == 11) Cf += (size_t)blockIdx.z * ((size_t)M * N);
#pragma unroll
  for (int mi = 0; mi < 8; ++mi)
#pragma unroll
    for (int rr = 0; rr < 4; ++rr) {
      const int row = m0 + wm * 128 + mi * 16 + l4 * 4 + rr;
#pragma unroll
      for (int ni = 0; ni < 4; ++ni) {
        const int col = n0 + wn * 64 + ni * 16 + l15;
        const size_t idx = (size_t)row * N + col;
        const float v = acc[mi][ni][rr];
        if constexpr (EPI == 11) {
          Cf[idx] = v;
        } else if constexpr (EPI == 3) {
          const float g = bf2f(aux[idx]);
          C16[idx] = f2bf(v * g / (1.f + __expf(-g)));
        } else if constexpr (EPI == 4) {
          C16[idx] = f2bf(slotw[row] * v);
        } else {
          C16[idx] = f2bf(v);
        }
      }
    }
}

// ---------------- GEMM_GU: fused gate+up, 256m x 128n-per-matrix, 8-phase ----------------
template <bool EXPERT>
__global__ __launch_bounds__(512, 2) void gemm_gu(
    const u16* __restrict__ A, const u16* __restrict__ Btg, const u16* __restrict__ Btu,
    u16* __restrict__ act, const int* __restrict__ slot_tok, const int* __restrict__ tiletab,
    int K, int LDC) {
  __shared__ char lds[131072];
  const int t = threadIdx.x, w = t >> 6, l = t & 63;
  int m0, nt;
  const u16 *Bg, *Bu;
  if constexpr (EXPERT) {
    const int ntil = tiletab[0];
    if ((int)blockIdx.y >= ntil) return;
    const int e = tiletab[1 + blockIdx.y * 2];
    m0 = tiletab[2 + blockIdx.y * 2];
    nt = blockIdx.x;
    const size_t boff = (size_t)e * LDC * K;
    Bg = Btg + boff;
    Bu = Btu + boff;
  } else {
    const int gx = gridDim.x;
    const int nwg = gx * 8;
    int wg = blockIdx.y * gx + blockIdx.x;
    wg = (wg & 7) * (nwg >> 3) + (wg >> 3);
    m0 = (wg & 7) * 256;
    nt = wg >> 3;
    Bg = Btg;
    Bu = Btu;
  }
  const int ktiles = K >> 6;
  const int wm = w >> 2, wn = w & 3;
  const int l15 = l & 15, l4 = l >> 4;
  const int sro = l >> 3, sc = l & 7;

  const u16* sga[2][2]; u32 sda[2][2];
#pragma unroll
  for (int h = 0; h < 2; ++h)
#pragma unroll
    for (int i = 0; i < 2; ++i) {
      const int q = i * 8 + w;
      const int r0 = ((q & 8) << 4) + h * 64 + (q & 7) * 8;
      const int r = r0 + sro;
      const int cl = sc ^ (r & 7);
      size_t arow;
      if constexpr (EXPERT) arow = (size_t)slot_tok[m0 + r];
      else arow = (size_t)(m0 + r);
      sga[h][i] = A + arow * K + cl * 8;
      sda[h][i] = (u32)(r0 * 128);
    }
  const u16* sgb[2][2]; u32 sdb[2][2];
#pragma unroll
  for (int mat = 0; mat < 2; ++mat)
#pragma unroll
    for (int i = 0; i < 2; ++i) {
      const int q = i * 8 + w;
      const int r0 = q * 8;
      const int r = r0 + sro;
      const int cl = sc ^ (r & 7);
      const u16* B = mat ? Bu : Bg;
      sgb[mat][i] = B + (size_t)(nt * 128 + r) * K + cl * 8;
      sdb[mat][i] = (u32)(32768 + mat * 16384 + r0 * 128);
    }
  auto stgA = [&](int b, int h, int kt) {
    const int kk = kt < ktiles ? kt : ktiles - 1;
#pragma unroll
    for (int i = 0; i < 2; ++i) gld16(sga[h][i] + kk * 64, lds + b * 65536 + sda[h][i]);
  };
  auto stgB = [&](int b, int mat, int kt) {
    const int kk = kt < ktiles ? kt : ktiles - 1;
#pragma unroll
    for (int i = 0; i < 2; ++i) gld16(sgb[mat][i] + kk * 64, lds + b * 65536 + sdb[mat][i]);
  };
  auto ldA = [&](int b, int mi, int ks) {
    const int row = wm * 128 + mi * 16 + l15;
    const int ch = (ks * 4 + l4) ^ (row & 7);
    return *(const bf16x8*)(lds + b * 65536 + row * 128 + ch * 16);
  };
  auto ldB = [&](int b, int mat, int ni, int ks) {
    const int row = wn * 32 + ni * 16 + l15;
    const int ch = (ks * 4 + l4) ^ (row & 7);
    return *(const bf16x8*)(lds + b * 65536 + 32768 + mat * 16384 + row * 128 + ch * 16);
  };

  f32x4 accg[8][2] = {}, accu[8][2] = {};
  bf16x8 aR[4][2], bg[2][2], bu[2][2];

  stgA(0, 0, 0); stgB(0, 0, 0); stgB(0, 1, 0); stgA(0, 1, 0);
  stgA(1, 0, 1); stgB(1, 1, 1); stgA(1, 1, 1);
  asm volatile("s_waitcnt vmcnt(6)" ::: "memory");
  __builtin_amdgcn_s_barrier();

  for (int kt = 0; kt < ktiles; kt += 2) {
#pragma unroll
    for (int mi = 0; mi < 4; ++mi) { aR[mi][0] = ldA(0, mi, 0); aR[mi][1] = ldA(0, mi, 1); }
#pragma unroll
    for (int ni = 0; ni < 2; ++ni) { bg[ni][0] = ldB(0, 0, ni, 0); bg[ni][1] = ldB(0, 0, ni, 1); }
    stgB(1, 0, kt + 1);
    __builtin_amdgcn_s_barrier();
    asm volatile("s_waitcnt lgkmcnt(0)" ::: "memory");
    __builtin_amdgcn_s_setprio(1);
#pragma unroll
    for (int mi = 0; mi < 4; ++mi)
#pragma unroll
      for (int ni = 0; ni < 2; ++ni) {
        MFMA16(accg[mi][ni], aR[mi][0], bg[ni][0]);
        MFMA16(accg[mi][ni], aR[mi][1], bg[ni][1]);
      }
    __builtin_amdgcn_s_setprio(0);
    __builtin_amdgcn_s_barrier();
#pragma unroll
    for (int ni = 0; ni < 2; ++ni) { bu[ni][0] = ldB(0, 1, ni, 0); bu[ni][1] = ldB(0, 1, ni, 1); }
    stgA(0, 0, kt + 2);
    __builtin_amdgcn_s_barrier();
    asm volatile("s_waitcnt lgkmcnt(0)" ::: "memory");
    __builtin_amdgcn_s_setprio(1);
#pragma unroll
    for (int mi = 0; mi < 4; ++mi)
#pragma unroll
      for (int ni = 0; ni < 2; ++ni) {
        MFMA16(accu[mi][ni], aR[mi][0], bu[ni][0]);
        MFMA16(accu[mi][ni], aR[mi][1], bu[ni][1]);
      }
    __builtin_amdgcn_s_setprio(0);
    __builtin_amdgcn_s_barrier();
#pragma unroll
    for (int mi = 0; mi < 4; ++mi) { aR[mi][0] = ldA(0, mi + 4, 0); aR[mi][1] = ldA(0, mi + 4, 1); }
    stgB(0, 1, kt + 2);
    __builtin_amdgcn_s_barrier();
    asm volatile("s_waitcnt lgkmcnt(0)" ::: "memory");
    __builtin_amdgcn_s_setprio(1);
#pragma unroll
    for (int mi = 0; mi < 4; ++mi)
#pragma unroll
      for (int ni = 0; ni < 2; ++ni) {
        MFMA16(accu[mi + 4][ni], aR[mi][0], bu[ni][0]);
        MFMA16(accu[mi + 4][ni], aR[mi][1], bu[ni][1]);
      }
    __builtin_amdgcn_s_setprio(0);
    __builtin_amdgcn_s_barrier();
    stgA(0, 1, kt + 2);
    __builtin_amdgcn_s_barrier();
    __builtin_amdgcn_s_setprio(1);
#pragma unroll
    for (int mi = 0; mi < 4; ++mi)
#pragma unroll
      for (int ni = 0; ni < 2; ++ni) {
        MFMA16(accg[mi + 4][ni], aR[mi][0], bg[ni][0]);
        MFMA16(accg[mi + 4][ni], aR[mi][1], bg[ni][1]);
      }
    __builtin_amdgcn_s_setprio(0);
    asm volatile("s_waitcnt vmcnt(6)" ::: "memory");
    __builtin_amdgcn_s_barrier();
#pragma unroll
    for (int mi = 0; mi < 4; ++mi) { aR[mi][0] = ldA(1, mi, 0); aR[mi][1] = ldA(1, mi, 1); }
#pragma unroll
    for (int ni = 0; ni < 2; ++ni) { bg[ni][0] = ldB(1, 0, ni, 0); bg[ni][1] = ldB(1, 0, ni, 1); }
    stgB(0, 0, kt + 2);
    __builtin_amdgcn_s_barrier();
    asm volatile("s_waitcnt lgkmcnt(0)" ::: "memory");
    __builtin_amdgcn_s_setprio(1);
#pragma unroll
    for (int mi = 0; mi < 4; ++mi)
#pragma unroll
      for (int ni = 0; ni < 2; ++ni) {
        MFMA16(accg[mi][ni], aR[mi][0], bg[ni][0]);
        MFMA16(accg[mi][ni], aR[mi][1], bg[ni][1]);
      }
    __builtin_amdgcn_s_setprio(0);
    __builtin_amdgcn_s_barrier();
#pragma unroll
    for (int ni = 0; ni < 2; ++ni) { bu[ni][0] = ldB(1, 1, ni, 0); bu[ni][1] = ldB(1, 1, ni, 1); }
    stgA(1, 0, kt + 3);
    __builtin_amdgcn_s_barrier();
    asm volatile("s_waitcnt lgkmcnt(0)" ::: "memory");
    __builtin_amdgcn_s_setprio(1);
#pragma unroll
    for (int mi = 0; mi < 4; ++mi)
#pragma unroll
      for (int ni = 0; ni < 2; ++ni) {
        MFMA16(accu[mi][ni], aR[mi][0], bu[ni][0]);
        MFMA16(accu[mi][ni], aR[mi][1], bu[ni][1]);
      }
    __builtin_amdgcn_s_setprio(0);
    __builtin_amdgcn_s_barrier();
#pragma unroll
    for (int mi = 0; mi < 4; ++mi) { aR[mi][0] = ldA(1, mi + 4, 0); aR[mi][1] = ldA(1, mi + 4, 1); }
    stgB(1, 1, kt + 3);
    __builtin_amdgcn_s_barrier();
    asm volatile("s_waitcnt lgkmcnt(0)" ::: "memory");
    __builtin_amdgcn_s_setprio(1);
#pragma unroll
    for (int mi = 0; mi < 4; ++mi)
#pragma unroll
      for (int ni = 0; ni < 2; ++ni) {
        MFMA16(accu[mi + 4][ni], aR[mi][0], bu[ni][0]);
        MFMA16(accu[mi + 4][ni], aR[mi][1], bu[ni][1]);
      }
    __builtin_amdgcn_s_setprio(0);
    __builtin_amdgcn_s_barrier();
    stgA(1, 1, kt + 3);
    __builtin_amdgcn_s_barrier();
    __builtin_amdgcn_s_setprio(1);
#pragma unroll
    for (int mi = 0; mi < 4; ++mi)
#pragma unroll
      for (int ni = 0; ni < 2; ++ni) {
        MFMA16(accg[mi + 4][ni], aR[mi][0], bg[ni][0]);
        MFMA16(accg[mi + 4][ni], aR[mi][1], bg[ni][1]);
      }
    __builtin_amdgcn_s_setprio(0);
    asm volatile("s_waitcnt vmcnt(6)" ::: "memory");
    __builtin_amdgcn_s_barrier();
  }

#pragma unroll
  for (int mi = 0; mi < 8; ++mi)
#pragma unroll
    for (int rr = 0; rr < 4; ++rr) {
      const int row = m0 + wm * 128 + mi * 16 + l4 * 4 + rr;
#pragma unroll
      for (int ni = 0; ni < 2; ++ni) {
        const int col = nt * 128 + wn * 32 + ni * 16 + l15;
        const float g = accg[mi][ni][rr];
        const float u = accu[mi][ni][rr];
        act[(size_t)row * LDC + col] = f2bf(u * g / (1.f + __expf(-g)));
      }
    }
}

// ---------------- split-K reduce (bf16 parts x4): dst = base + sum ----------------
__global__ __launch_bounds__(256) void redbf_k(float* __restrict__ dst,
                                               const float* __restrict__ base,
                                               const u16* __restrict__ parts) {
  const int i = blockIdx.x * 256 + threadIdx.x;
  float s[8];
  const float* bp = base + (size_t)i * 8;
#pragma unroll
  for (int j = 0; j < 8; ++j) s[j] = bp[j];
#pragma unroll
  for (int p = 0; p < 4; ++p) {
    u16x8 v = ((const u16x8*)parts)[(size_t)p * 524288 + i];
#pragma unroll
    for (int j = 0; j < 8; ++j) s[j] += bf2f(v[j]);
  }
  float* dp = dst + (size_t)i * 8;
#pragma unroll
  for (int j = 0; j < 8; ++j) dp[j] = s[j];
}

// ---------------- RoPE + pack Q/K/V + new_k/new_v + fused wsg/wsu transpose (y==2) ------
__global__ __launch_bounds__(256) void rope_k(
    const u16* __restrict__ p0, const u16* __restrict__ p1,
    const float* __restrict__ cosb, const float* __restrict__ sinb,
    const float* __restrict__ bq, const float* __restrict__ bk, const float* __restrict__ bv,
    u16* __restrict__ QR, u16* __restrict__ KR, u16* __restrict__ VB,
    float* __restrict__ NK, float* __restrict__ NV,
    const float* __restrict__ wsg, const float* __restrict__ wsu,
    u16* __restrict__ WTSg, u16* __restrict__ WTSu) {
  __shared__ u16 tile[64 * 80];
  const int t = threadIdx.x;
  if (blockIdx.y == 2) {
    const int bi = blockIdx.x;   // [0,1024): 11008 tiles total, 11 per block
#pragma unroll 1
    for (int i = 0; i < 11; ++i) {
      const int ti = bi * 11 + i;
      if (ti >= 11008) break;
      if (ti < 5504) {
        ttile(wsg, WTSg, 2048, FSH, (ti % 172) * 64, (ti / 172) * 64, tile, t);
      } else {
        const int r = ti - 5504;
        ttile(wsu, WTSu, 2048, FSH, (r % 172) * 64, (r / 172) * 64, tile, t);
      }
      __syncthreads();
    }
    return;
  }
  const int s = blockIdx.x, b = blockIdx.y;
  const size_t tok = (size_t)b * 1024 + s;
  const u16* r0 = p0 + tok * 3072;
  const u16* r1 = p1 + tok * 3072;
  const float* cr = cosb + s * 128;
  const float* sr = sinb + s * 128;
  for (int i = t; i < 1024; i += 256) {
    const int h = i >> 6, d = i & 63;
    const float v1 = bf2f(r0[h * 128 + d]) + bf2f(r1[h * 128 + d]) + bq[h * 128 + d];
    const float v2 = bf2f(r0[h * 128 + d + 64]) + bf2f(r1[h * 128 + d + 64]) + bq[h * 128 + d + 64];
    const float o1 = v1 * cr[d] - v2 * sr[d];
    const float o2 = v2 * cr[d + 64] + v1 * sr[d + 64];
    const size_t qb = (((size_t)(b * 16 + h)) * 1024 + s) * 128;
    QR[qb + d] = f2bf(o1);
    QR[qb + d + 64] = f2bf(o2);
  }
  {
    const int h = t >> 6, d = t & 63;
    const float v1 = bf2f(r0[2048 + h * 128 + d]) + bf2f(r1[2048 + h * 128 + d]) + bk[h * 128 + d];
    const float v2 = bf2f(r0[2048 + h * 128 + d + 64]) + bf2f(r1[2048 + h * 128 + d + 64]) + bk[h * 128 + d + 64];
    const float o1 = v1 * cr[d] - v2 * sr[d];
    const float o2 = v2 * cr[d + 64] + v1 * sr[d + 64];
    const size_t kb = (((size_t)(b * 4 + h)) * 1024 + s) * 128;
    KR[kb + d] = f2bf(o1);
    KR[kb + d + 64] = f2bf(o2);
    const size_t ob = tok * 2048;
#pragma unroll
    for (int rep = 0; rep < 4; ++rep) {
      NK[ob + (h * 4 + rep) * 128 + d] = o1;
      NK[ob + (h * 4 + rep) * 128 + d + 64] = o2;
    }
  }
  for (int i = t; i < 512; i += 256) {
    const int h = i >> 7, d = i & 127;
    const float v = bf2f(r0[2560 + i]) + bf2f(r1[2560 + i]) + bv[i];
    VB[(((size_t)(b * 4 + h)) * 1024 + s) * 128 + d] = f2bf(v);
    const size_t ob = tok * 2048;
#pragma unroll
    for (int rep = 0; rep < 4; ++rep) NV[ob + (h * 4 + rep) * 128 + d] = v;
  }
}

// ---------------- Flash attention + fused wd/wg/wu/wo transposes (z>=2 planes) ----------
__global__ __launch_bounds__(256) void attn_k(const u16* __restrict__ Q,
                                              const u16* __restrict__ Kc,
                                              const u16* __restrict__ Vc,
                                              u16* __restrict__ O,
                                              const float* __restrict__ wdsrc, u16* __restrict__ wtd,
                                              const float* __restrict__ wgsrc, u16* __restrict__ wtg,
                                              const float* __restrict__ wusrc, u16* __restrict__ wtu,
                                              const float* __restrict__ wosrc, u16* __restrict__ wto) {
  __shared__ u16 Ks[64 * 128];
  __shared__ u16 Vt[128 * 66];
  __shared__ u16 Ps[4][16 * 68];
  const int t = threadIdx.x, w = t >> 6, l = t & 63;
  if (blockIdx.z >= 2) {
    u16* tile = Ks;  // 64*80 <= 64*128
    const int bi = blockIdx.y * 16 + blockIdx.x;   // [0,256)
    if (blockIdx.z <= 4) {
      // 8 experts x 2048^2 each = 8192 tiles; 32 per block
      const float* src = blockIdx.z == 2 ? wdsrc : (blockIdx.z == 3 ? wgsrc : wusrc);
      u16* dst = blockIdx.z == 2 ? wtd : (blockIdx.z == 3 ? wtg : wtu);
#pragma unroll 1
      for (int i = 0; i < 32; ++i) {
        const int ti = bi * 32 + i;
        const int e = ti >> 10, rem = ti & 1023;
        ttile(src + (size_t)e * 4194304, dst + (size_t)e * 4194304,
              2048, 2048, (rem & 31) * 64, (rem >> 5) * 64, tile, t);
        __syncthreads();
      }
    } else {
      // wo: 1024 tiles; 4 per block
#pragma unroll 1
      for (int i = 0; i < 4; ++i) {
        const int ti = bi * 4 + i;
        ttile(wosrc, wto, 2048, 2048, (ti & 31) * 64, (ti >> 5) * 64, tile, t);
        __syncthreads();
      }
    }
    return;
  }
  const int qt = blockIdx.x, h = blockIdx.y, b = blockIdx.z;
  const int kvh = h >> 2;
  const int l15 = l & 15, l4 = l >> 4;
  bf16x8 qf[4];
  {
    const u16* qb = Q + (((size_t)(b * 16 + h)) * 1024 + qt * 64 + w * 16 + l15) * 128 + l4 * 8;
#pragma unroll
    for (int c = 0; c < 4; ++c) qf[c] = *(const bf16x8*)(qb + c * 32);
  }
  float m_run[4] = {-1e30f, -1e30f, -1e30f, -1e30f};
  float l_run[4] = {0.f, 0.f, 0.f, 0.f};
  f32x4 accO[8] = {};
  const size_t kvbase = ((size_t)(b * 4 + kvh)) * 1024 * 128;
  const int ntiles = qt + 1;
  for (int kt = 0; kt < ntiles; ++kt) {
    __syncthreads();
    {
      const int key = t >> 2;
      const u16* kg = Kc + kvbase + (size_t)(kt * 64 + key) * 128;
      const u16* vg = Vc + kvbase + (size_t)(kt * 64 + key) * 128;
      const int sw = (key & 7) << 4;
#pragma unroll
      for (int p = 0; p < 4; ++p) {
        const int ch = (t & 3) * 4 + p;
        *(u16x8*)((char*)Ks + key * 256 + ((ch * 16) ^ sw)) = *(const u16x8*)(kg + ch * 8);
        const int d0 = ch * 8;
        u16x8 vv = *(const u16x8*)(vg + d0);
#pragma unroll
        for (int j = 0; j < 8; ++j) Vt[(d0 + j) * 66 + key] = vv[j];
      }
    }
    __syncthreads();
    f32x4 sf[4] = {};
    __builtin_amdgcn_s_setprio(1);
#pragma unroll
    for (int nf = 0; nf < 4; ++nf) {
      const int keyl = nf * 16 + l15;
      const int sw = (keyl & 7) << 4;
      const char* kbase = (const char*)Ks + keyl * 256;
#pragma unroll
      for (int c = 0; c < 4; ++c) {
        bf16x8 kf = *(const bf16x8*)(kbase + ((c * 64 + l4 * 16) ^ sw));
        sf[nf] = __builtin_amdgcn_mfma_f32_16x16x32_bf16(qf[c], kf, sf[nf], 0, 0, 0);
      }
    }
    __builtin_amdgcn_s_setprio(0);
    const int qg0 = qt * 64 + w * 16 + l4 * 4;
    float alpha[4];
#pragma unroll
    for (int r = 0; r < 4; ++r) {
      const int qg = qg0 + r;
      float tm = -1e30f;
#pragma unroll
      for (int nf = 0; nf < 4; ++nf) {
        const int kg = kt * 64 + nf * 16 + l15;
        float sv = sf[nf][r] * 0.088388347648318447f;
        sv = (kg <= qg) ? sv : -1e30f;
        sf[nf][r] = sv;
        tm = fmaxf(tm, sv);
      }
#pragma unroll
      for (int mm = 1; mm < 16; mm <<= 1) tm = fmaxf(tm, __shfl_xor(tm, mm));
      const float mn = fmaxf(m_run[r], tm);
      alpha[r] = __expf(m_run[r] - mn);
      m_run[r] = mn;
      float rs = 0.f;
#pragma unroll
      for (int nf = 0; nf < 4; ++nf) {
        const float p = __expf(sf[nf][r] - mn);
        sf[nf][r] = p;
        rs += p;
      }
#pragma unroll
      for (int mm = 1; mm < 16; mm <<= 1) rs += __shfl_xor(rs, mm);
      l_run[r] = l_run[r] * alpha[r] + rs;
    }
#pragma unroll
    for (int nf = 0; nf < 8; ++nf)
#pragma unroll
      for (int r = 0; r < 4; ++r) accO[nf][r] *= alpha[r];
#pragma unroll
    for (int nf = 0; nf < 4; ++nf)
#pragma unroll
      for (int r = 0; r < 4; ++r)
        Ps[w][(l4 * 4 + r) * 68 + nf * 16 + l15] = f2bf(sf[nf][r]);
    __syncthreads();
    __builtin_amdgcn_s_setprio(1);
#pragma unroll
    for (int kc = 0; kc < 2; ++kc) {
      const u16* pb = &Ps[w][0] + l15 * 68 + kc * 32 + l4 * 8;
      union { u16x4 q[2]; bf16x8 v; } pu;
      pu.q[0] = *(const u16x4*)pb;
      pu.q[1] = *(const u16x4*)(pb + 4);
#pragma unroll
      for (int nf = 0; nf < 8; ++nf) {
        const int dd = nf * 16 + l15;
        const u16* vp = &Vt[0] + dd * 66 + kc * 32 + l4 * 8;
        union { u32 u[4]; bf16x8 v; } vu;
        vu.u[0] = *(const u32*)(vp);
        vu.u[1] = *(const u32*)(vp + 2);
        vu.u[2] = *(const u32*)(vp + 4);
        vu.u[3] = *(const u32*)(vp + 6);
        accO[nf] = __builtin_amdgcn_mfma_f32_16x16x32_bf16(pu.v, vu.v, accO[nf], 0, 0, 0);
      }
    }
    __builtin_amdgcn_s_setprio(0);
  }
  const int qg0 = qt * 64 + w * 16 + l4 * 4;
#pragma unroll
  for (int nf = 0; nf < 8; ++nf) {
    const int dd = nf * 16 + l15;
#pragma unroll
    for (int r = 0; r < 4; ++r) {
      const float o = accO[nf][r] / l_run[r];
      O[((size_t)(b * 1024 + qg0 + r)) * 2048 + h * 128 + dd] = f2bf(o);
    }
  }
}

// ---------------- Fused residual+rmsnorm+router + fused wsd transpose (tail blocks) ----
__global__ __launch_bounds__(256) void fuserouter_k(
    const float* __restrict__ x, const float* __restrict__ parts,
    const float* __restrict__ wn, const float* __restrict__ rw,
    float* __restrict__ X2, u16* __restrict__ HN,
    int* __restrict__ topi2, float* __restrict__ topw2, float* __restrict__ probs,
    const float* __restrict__ wsdsrc, u16* __restrict__ wtsd) {
  __shared__ u16 tile[64 * 80];
  __shared__ float red[4];
  __shared__ float racc[32];
  const int t = threadIdx.x, w = t >> 6;
  if ((int)blockIdx.x >= TT) {
    const int bi = blockIdx.x - TT;   // 344 blocks x 16 tiles = 5504
#pragma unroll 1
    for (int i = 0; i < 16; ++i) {
      const int ti = bi * 16 + i;
      ttile(wsdsrc, wtsd, FSH, 2048, (ti & 31) * 64, (ti >> 5) * 64, tile, t);
      __syncthreads();
    }
    return;
  }
  const int tok = blockIdx.x;
  const size_t base = (size_t)tok * DD + t * 8;
  float v[8];
  {
    float4 a = *(const float4*)(x + base);
    float4 b = *(const float4*)(x + base + 4);
    v[0] = a.x; v[1] = a.y; v[2] = a.z; v[3] = a.w;
    v[4] = b.x; v[5] = b.y; v[6] = b.z; v[7] = b.w;
  }
#pragma unroll
  for (int p = 0; p < 4; ++p) {
    const float* pr = parts + (size_t)p * (TT * DD) + base;
    float4 a = *(const float4*)(pr);
    float4 b = *(const float4*)(pr + 4);
    v[0] += a.x; v[1] += a.y; v[2] += a.z; v[3] += a.w;
    v[4] += b.x; v[5] += b.y; v[6] += b.z; v[7] += b.w;
  }
  *(float4*)(X2 + base) = make_float4(v[0], v[1], v[2], v[3]);
  *(float4*)(X2 + base + 4) = make_float4(v[4], v[5], v[6], v[7]);
  float ss = 0.f;
#pragma unroll
  for (int j = 0; j < 8; ++j) ss += v[j] * v[j];
#pragma unroll
  for (int m = 1; m < 64; m <<= 1) ss += __shfl_xor(ss, m);
  if ((t & 63) == 0) red[w] = ss;
  __syncthreads();
  const float sc = rsqrtf((red[0] + red[1] + red[2] + red[3]) * (1.f / DD) + 1e-6f);
  float hn[8];
  u16x8 o;
#pragma unroll
  for (int j = 0; j < 8; ++j) {
    hn[j] = v[j] * sc * wn[t * 8 + j];
    o[j] = f2bf(hn[j]);
  }
  *(u16x8*)(HN + base) = o;
  float acc[8] = {};
#pragma unroll
  for (int j = 0; j < 8; ++j) {
    const int d = t * 8 + j;
    float4 r0 = *(const float4*)(rw + d * 8);
    float4 r1 = *(const float4*)(rw + d * 8 + 4);
    acc[0] += hn[j] * r0.x; acc[1] += hn[j] * r0.y; acc[2] += hn[j] * r0.z; acc[3] += hn[j] * r0.w;
    acc[4] += hn[j] * r1.x; acc[5] += hn[j] * r1.y; acc[6] += hn[j] * r1.z; acc[7] += hn[j] * r1.w;
  }
#pragma unroll
  for (int m = 1; m < 64; m <<= 1)
#pragma unroll
    for (int e = 0; e < 8; ++e) acc[e] += __shfl_xor(acc[e], m);
  if ((t & 63) == 0)
#pragma unroll
    for (int e = 0; e < 8; ++e) racc[w * 8 + e] = acc[e];
  __syncthreads();
  if (t == 0) {
    float lg[8];
#pragma unroll
    for (int e = 0; e < 8; ++e) lg[e] = racc[e] + racc[8 + e] + racc[16 + e] + racc[24 + e];
    float mx = lg[0];
#pragma unroll
    for (int e = 1; e < 8; ++e) mx = fmaxf(mx, lg[e]);
    float p[8], sum = 0.f;
#pragma unroll
    for (int e = 0; e < 8; ++e) { p[e] = __expf(lg[e] - mx); sum += p[e]; }
    const float inv = 1.f / sum;
#pragma unroll
    for (int e = 0; e < 8; ++e) p[e] *= inv;
    *(float4*)(probs + tok * 8) = make_float4(p[0], p[1], p[2], p[3]);
    *(float4*)(probs + tok * 8 + 4) = make_float4(p[4], p[5], p[6], p[7]);
    int e0 = 0; float v0 = p[0];
#pragma unroll
    for (int e = 1; e < 8; ++e) if (p[e] > v0) { v0 = p[e]; e0 = e; }
    int e1 = (e0 == 0) ? 1 : 0; float v1 = p[e1];
#pragma unroll
    for (int e = 0; e < 8; ++e) if (e != e0 && p[e] > v1) { v1 = p[e]; e1 = e; }
    const float wsum = v0 + v1;
    topi2[tok * 2] = e0; topi2[tok * 2 + 1] = e1;
    topw2[tok * 2] = v0 / wsum; topw2[tok * 2 + 1] = v1 / wsum;
  }
}

__global__ __launch_bounds__(256) void zero_k(int* __restrict__ slot_tok,
                                              float* __restrict__ slot_w) {
  const int i = blockIdx.x * 256 + threadIdx.x;
  if (i < 6144) { slot_tok[i] = 0; slot_w[i] = 0.f; }
}

// ---------------- scan2: counts+pmean reduction + 256-row tile table ----------------
__global__ __launch_bounds__(256) void scan2_k(const int* __restrict__ topi2,
                                               const float* __restrict__ probs,
                                               int* __restrict__ cursors,
                                               int* __restrict__ tiletab,
                                               float* __restrict__ auxout) {
  const int t = threadIdx.x, w = t >> 6, l = t & 63;
  __shared__ int cnt[8];
  __shared__ float wsum[4][8];
  if (t < 8) cnt[t] = 0;
  __syncthreads();
  float ps[8] = {};
  for (int i = t; i < 2048; i += 256) {
    atomicAdd(&cnt[topi2[i * 2]], 1);
    atomicAdd(&cnt[topi2[i * 2 + 1]], 1);
    float4 a = *(const float4*)(probs + i * 8);
    float4 b = *(const float4*)(probs + i * 8 + 4);
    ps[0] += a.x; ps[1] += a.y; ps[2] += a.z; ps[3] += a.w;
    ps[4] += b.x; ps[5] += b.y; ps[6] += b.z; ps[7] += b.w;
  }
#pragma unroll
  for (int m = 1; m < 64; m <<= 1)
#pragma unroll
    for (int e = 0; e < 8; ++e) ps[e] += __shfl_xor(ps[e], m);
  if (l == 0)
#pragma unroll
    for (int e = 0; e < 8; ++e) wsum[w][e] = ps[e];
  __syncthreads();
  if (t == 0) {
    int off = 0, nt = 0;
    float aux = 0.f;
    for (int e = 0; e < 8; ++e) {
      cursors[e] = off;
      const int c = cnt[e];
      const int nte = (c + 255) >> 8;
      for (int i = 0; i < nte; ++i) {
        tiletab[1 + nt * 2] = e;
        tiletab[2 + nt * 2] = off + i * 256;
        ++nt;
      }
      off += nte * 256;
      const float pm = (wsum[0][e] + wsum[1][e] + wsum[2][e] + wsum[3][e]) * (1.f / 2048.f);
      aux += ((float)c * (1.f / 4096.f)) * pm;
    }
    tiletab[0] = nt;
    *auxout = 8.f * aux;
  }
}

// ---------------- assign: LDS-local rank, 8 global atomics per block ----------------
__global__ __launch_bounds__(256) void assign_k(const int* __restrict__ topi2,
                                                const float* __restrict__ topw2,
                                                int* __restrict__ cursors,
                                                int* __restrict__ slot_tok,
                                                float* __restrict__ slot_w,
                                                int* __restrict__ tok_slot) {
  __shared__ int lcnt[8];
  __shared__ int base[8];
  const int t = threadIdx.x;
  const int tok = blockIdx.x * 256 + t;
  if (t < 8) lcnt[t] = 0;
  __syncthreads();
  int e[2], lr[2];
#pragma unroll
  for (int j = 0; j < 2; ++j) {
    e[j] = topi2[tok * 2 + j];
    lr[j] = atomicAdd(&lcnt[e[j]], 1);
  }
  __syncthreads();
  if (t < 8) base[t] = atomicAdd(&cursors[t], lcnt[t]);
  __syncthreads();
#pragma unroll
  for (int j = 0; j < 2; ++j) {
    const int s = base[e[j]] + lr[j];
    slot_tok[s] = tok;
    slot_w[s] = topw2[tok * 2 + j];
    tok_slot[tok * 2 + j] = s;
  }
}

// ---------------- final: out += routed[s0] + routed[s1] ----------------
__global__ __launch_bounds__(256) void final_k(float* __restrict__ out,
                                               const u16* __restrict__ routed,
                                               const int* __restrict__ tok_slot) {
  const int tok = blockIdx.x, t = threadIdx.x;
  const int s0 = tok_slot[tok * 2], s1 = tok_slot[tok * 2 + 1];
  u16x8 a = ((const u16x8*)(routed + (size_t)s0 * DD))[t];
  u16x8 b = ((const u16x8*)(routed + (size_t)s1 * DD))[t];
  float* o = out + (size_t)tok * DD + t * 8;
  float4 o0 = *(const float4*)o;
  float4 o1 = *(const float4*)(o + 4);
  o0.x += bf2f(a[0]) + bf2f(b[0]); o0.y += bf2f(a[1]) + bf2f(b[1]);
  o0.z += bf2f(a[2]) + bf2f(b[2]); o0.w += bf2f(a[3]) + bf2f(b[3]);
  o1.x += bf2f(a[4]) + bf2f(b[4]); o1.y += bf2f(a[5]) + bf2f(b[5]);
  o1.z += bf2f(a[6]) + bf2f(b[6]); o1.w += bf2f(a[7]) + bf2f(b[7]);
  *(float4*)o = o0;
  *(float4*)(o + 4) = o1;
}

extern "C" void kernel_launch(void* const* d_in, const int* in_sizes, int n_in,
                              void* d_out, int out_size, void* d_ws, size_t ws_size,
                              hipStream_t stream) {
  (void)in_sizes; (void)n_in; (void)out_size; (void)ws_size;
  const float* x    = (const float*)d_in[0];
  const float* rc   = (const float*)d_in[1];
  const float* rs   = (const float*)d_in[2];
  const float* anw  = (const float*)d_in[3];
  const float* fnw  = (const float*)d_in[4];
  const float* wq   = (const float*)d_in[5];
  const float* bq   = (const float*)d_in[6];
  const float* wk   = (const float*)d_in[7];
  const float* bk   = (const float*)d_in[8];
  const float* wv   = (const float*)d_in[9];
  const float* bv   = (const float*)d_in[10];
  const float* wo   = (const float*)d_in[11];
  const float* rw   = (const float*)d_in[12];
  const float* wg   = (const float*)d_in[13];
  const float* wu   = (const float*)d_in[14];
  const float* wd   = (const float*)d_in[15];
  const float* wsg  = (const float*)d_in[16];
  const float* wsu  = (const float*)d_in[17];
  const float* wsd  = (const float*)d_in[18];

  // Workspace ~733 MB; dedicated regions, no aliasing.
  const size_t MB = (size_t)1 << 20;
  char* ws = (char*)d_ws;
  float* X2     = (float*)(ws + 0);          // 16
  u16*   HN     = (u16*)(ws + 16 * MB);      // 8
  char*  SM     = ws + 24 * MB;              // 1
  u16*   H      = (u16*)(ws + 25 * MB);      // 8
  u16*   WTQ    = (u16*)(ws + 33 * MB);      // 12
  u16*   PARTSQ = (u16*)(ws + 46 * MB);      // 26
  u16*   QR     = (u16*)(ws + 72 * MB);      // 8
  u16*   KR     = (u16*)(ws + 80 * MB);      // 2
  u16*   VBb    = (u16*)(ws + 82 * MB);      // 2
  u16*   ATTNO  = (u16*)(ws + 84 * MB);      // 8
  u16*   WTO    = (u16*)(ws + 92 * MB);      // 8
  float* PARTSW = (float*)(ws + 100 * MB);   // 64
  u16*   WTSg   = (u16*)(ws + 164 * MB);     // 44
  u16*   WTSu   = (u16*)(ws + 208 * MB);     // 44
  u16*   G      = (u16*)(ws + 252 * MB);     // 44
  u16*   WTSd   = (u16*)(ws + 296 * MB);     // 44
  u16*   PARTSD = (u16*)(ws + 340 * MB);     // 32
  u16*   WTEg   = (u16*)(ws + 372 * MB);     // 64
  u16*   WTEu   = (u16*)(ws + 436 * MB);     // 64
  u16*   WTEd   = (u16*)(ws + 500 * MB);     // 64
  u16*   ACT    = (u16*)(ws + 564 * MB);     // 24
  u16*   ROUTED = (u16*)(ws + 588 * MB);     // 24

  int*   CURS  = (int*)(SM + 256);
  int*   TILT  = (int*)(SM + 512);
  int*   TOPI  = (int*)(SM + 4096);
  float* TOPW  = (float*)(SM + 40960);
  int*   STOK  = (int*)(SM + 73728);
  float* SW    = (float*)(SM + 98304);
  int*   TSLOT = (int*)(SM + 131072);
  float* PROBS = (float*)(SM + 163840);

  float* out  = (float*)d_out;
  float* NK   = out + 4194304;
  float* NV   = out + 2 * 4194304;
  float* AUXO = out + 3 * 4194304;

  const dim3 b256(256);
  const dim3 b512(512);

  // P1: rmsnorm (+wq/wk/wv transpose in tail) + QKV gemm8
  rmsnorm_k<<<TT + 192, b256, 0, stream>>>(x, anw, H, wq, wk, wv, WTQ);
  gemm8<10, true, false><<<dim3(12, 8, 2), b512, 0, stream>>>(
      H, WTQ, PARTSQ, nullptr, nullptr, nullptr, TT, 3072, 2048, 1024);
  // P2: rope (+wsg/wsu transpose on y==2 plane) + attention (+wd/wg/wu/wo on z>=2 planes)
  rope_k<<<dim3(1024, 3), b256, 0, stream>>>(PARTSQ, PARTSQ + (size_t)TT * 3072, rc, rs,
                                             bq, bk, bv, QR, KR, VBb, NK, NV,
                                             wsg, wsu, WTSg, WTSu);
  attn_k<<<dim3(16, 16, 6), b256, 0, stream>>>(QR, KR, VBb, ATTNO,
                                               wd, WTEd, wg, WTEg, wu, WTEu, wo, WTO);
  // P3: wo projection (gemm8 split-K x4, f32 parts)
  gemm8<11, true, false><<<dim3(8, 8, 4), b512, 0, stream>>>(
      ATTNO, WTO, PARTSW, nullptr, nullptr, nullptr, TT, 2048, 2048, 512);
  // P4: fused residual+rmsnorm+router (+wsd transpose in tail); scan; assign
  zero_k<<<24, b256, 0, stream>>>(STOK, SW);
  fuserouter_k<<<TT + 344, b256, 0, stream>>>(x, PARTSW, fnw, rw, X2, HN, TOPI, TOPW, PROBS,
                                              wsd, WTSd);
  scan2_k<<<1, b256, 0, stream>>>(TOPI, PROBS, CURS, TILT, AUXO);
  assign_k<<<8, b256, 0, stream>>>(TOPI, TOPW, CURS, STOK, SW, TSLOT);
  // P5: shared expert — fused gate+up, then down (split-K x4), reduce into out
  gemm_gu<false><<<dim3(86, 8, 1), b512, 0, stream>>>(
      HN, WTSg, WTSu, G, nullptr, nullptr, 2048, FSH);
  gemm8<10, true, false><<<dim3(8, 8, 4), b512, 0, stream>>>(
      G, WTSd, PARTSD, nullptr, nullptr, nullptr, TT, 2048, FSH, 2816);
  redbf_k<<<2048, b256, 0, stream>>>(out, X2, PARTSD);
  // P6: routed experts — fused gate+up over all 8 experts, then down
  gemm_gu<true><<<dim3(16, 24, 1), b512, 0, stream>>>(
      HN, WTEg, WTEu, ACT, STOK, TILT, 2048, 2048);
  gemm8<4, false, true><<<dim3(8, 24, 1), b512, 0, stream>>>(
      ACT, WTEd, ROUTED, nullptr, SW, TILT, 0, 2048, 2048, 0);
  // P7: out += routed
  final_k<<<TT, b256, 0, stream>>>(out, ROUTED, TSLOT);
}

// Round 12
// 845.902 us; speedup vs baseline: 1.0287x; 1.0287x over previous
//
#include <hip/hip_runtime.h>

typedef unsigned short u16;
typedef unsigned int u32;
typedef unsigned long long u64;
typedef __attribute__((ext_vector_type(4))) unsigned short u16x4;
typedef __attribute__((ext_vector_type(8))) unsigned short u16x8;
typedef __attribute__((ext_vector_type(4))) float f32x4;
typedef __attribute__((ext_vector_type(8))) __bf16 bf16x8;

#define DD 2048
#define TT 2048
#define FSH 11008

__device__ __forceinline__ float bf2f(u16 u) {
  union { u32 i; float f; } v; v.i = ((u32)u) << 16; return v.f;
}
__device__ __forceinline__ u16 f2bf(float f) {
  union { float f; u32 i; } v; v.f = f;
  u32 r = v.i + 0x7fffu + ((v.i >> 16) & 1u);
  return (u16)(r >> 16);
}
__device__ __forceinline__ void gld16(const void* g, void* l) {
  __builtin_amdgcn_global_load_lds((const __attribute__((address_space(1))) void*)g,
                                   (__attribute__((address_space(3))) void*)l, 16, 0, 0);
}

#define MFMA16(d, a, b) d = __builtin_amdgcn_mfma_f32_16x16x32_bf16(a, b, d, 0, 0, 0)

// ---------------- 64x64 tile transpose helper (256 threads, XOR-swizzled LDS) ----------
__device__ __forceinline__ void ttile(const float* __restrict__ Wm, u16* __restrict__ Wtm,
                                      int R, int C, int n0, int k0, u16* tile, int t) {
#pragma unroll
  for (int p = 0; p < 4; ++p) {
    const int kk = (t >> 4) + p * 16;
    const int nn = (t & 15) * 4;
    float4 v = *(const float4*)(Wm + (size_t)(k0 + kk) * C + n0 + nn);
    const float vv[4] = {v.x, v.y, v.z, v.w};
#pragma unroll
    for (int j = 0; j < 4; ++j) {
      const int n = nn + j;
      tile[n * 80 + (kk ^ (((n >> 2) & 7) << 3))] = f2bf(vv[j]);
    }
  }
  __syncthreads();
#pragma unroll
  for (int p = 0; p < 2; ++p) {
    const int n = (t >> 3) + p * 32;
    const int c = t & 7;
    u16x8 v = *(const u16x8*)(tile + n * 80 + ((c * 8) ^ (((n >> 2) & 7) << 3)));
    *(u16x8*)(Wtm + (size_t)(n0 + n) * R + k0 + c * 8) = v;
  }
}

// ---------------- RMSNorm: f32 row -> bf16 row ----------------
__global__ __launch_bounds__(256) void rmsnorm_k(const float* __restrict__ x,
                                                 const float* __restrict__ w,
                                                 u16* __restrict__ out) {
  const int t = threadIdx.x;
  const float* xr = x + (size_t)blockIdx.x * DD;
  float4 a = *(const float4*)(xr + t * 8);
  float4 b = *(const float4*)(xr + t * 8 + 4);
  float ss = a.x*a.x + a.y*a.y + a.z*a.z + a.w*a.w
           + b.x*b.x + b.y*b.y + b.z*b.z + b.w*b.w;
#pragma unroll
  for (int m = 1; m < 64; m <<= 1) ss += __shfl_xor(ss, m);
  __shared__ float red[4];
  if ((t & 63) == 0) red[t >> 6] = ss;
  __syncthreads();
  float sc = rsqrtf((red[0] + red[1] + red[2] + red[3]) * (1.f / DD) + 1e-6f);
  float4 wa = *(const float4*)(w + t * 8);
  float4 wb = *(const float4*)(w + t * 8 + 4);
  u16x8 o;
  o[0] = f2bf(a.x * sc * wa.x); o[1] = f2bf(a.y * sc * wa.y);
  o[2] = f2bf(a.z * sc * wa.z); o[3] = f2bf(a.w * sc * wa.w);
  o[4] = f2bf(b.x * sc * wb.x); o[5] = f2bf(b.y * sc * wb.y);
  o[6] = f2bf(b.z * sc * wb.z); o[7] = f2bf(b.w * sc * wb.w);
  *(u16x8*)(out + (size_t)blockIdx.x * DD + t * 8) = o;
}

// ---------------- Standalone transpose+convert: W[R][C] f32 -> Wt[C][R] bf16 ----------
__global__ __launch_bounds__(256) void transp_k(const float* __restrict__ W,
                                                u16* __restrict__ Wt, int R, int C) {
  __shared__ u16 tile[64 * 80];
  const size_t msz = (size_t)R * C;
  ttile(W + msz * blockIdx.z, Wt + msz * blockIdx.z, R, C,
        blockIdx.x * 64, blockIdx.y * 64, tile, threadIdx.x);
}

// ---------------- GEMM8: 256^2, 8-wave, 8-phase ----------------
// EPI: 2=bf16, 3=bf16 silu(aux)*acc, 4=bf16 slotw[row]*acc, 10=bf16 parts, 11=f32 parts
template <int EPI, bool SPLITK, bool EXPERT>
__global__ __launch_bounds__(512, 2) void gemm8(
    const u16* __restrict__ A, const u16* __restrict__ Bt, void* __restrict__ Cp,
    const u16* __restrict__ aux, const float* __restrict__ slotw,
    const int* __restrict__ tiletab, int M, int N, int K, int Kc) {
  __shared__ char lds[131072];
  const int t = threadIdx.x, w = t >> 6, l = t & 63;
  int m0, n0;
  if constexpr (EXPERT) {
    const int ntil = tiletab[0];
    if ((int)blockIdx.y >= ntil) return;
    const int e = tiletab[1 + blockIdx.y * 2];
    m0 = tiletab[2 + blockIdx.y * 2];
    n0 = blockIdx.x * 256;
    Bt += (size_t)e * N * K;
  } else {
    const int gx = gridDim.x, gy = gridDim.y;
    const int nwg = gx * gy;          // % 8 == 0
    int wg = blockIdx.y * gx + blockIdx.x;
    wg = (wg & 7) * (nwg >> 3) + (wg >> 3);   // XCD swizzle (bijective)
    m0 = (wg % gy) * 256;             // n-major
    n0 = (wg / gy) * 256;
  }
  int kbase = 0, KC = K;
  if constexpr (SPLITK) {
    kbase = blockIdx.z * Kc;
    const int rem = K - kbase;
    KC = rem < Kc ? rem : Kc;
  }
  const int ktiles = KC >> 6;
  const int wm = w >> 2, wn = w & 3;
  const int l15 = l & 15, l4 = l >> 4;
  const int sro = l >> 3, sc = l & 7;

  const u16* sgp[2][2][2];
  u32 sdo[2][2][2];
#pragma unroll
  for (int isB = 0; isB < 2; ++isB)
#pragma unroll
    for (int h = 0; h < 2; ++h)
#pragma unroll
      for (int i = 0; i < 2; ++i) {
        const int q = i * 8 + w;
        const int r0 = isB ? (((q >> 2) << 6) + h * 32 + (q & 3) * 8)
                           : (((q & 8) << 4) + h * 64 + (q & 7) * 8);
        const int r = r0 + sro;
        const int cl = sc ^ (r & 7);
        const u16* base = isB ? (Bt + (size_t)(n0 + r) * K) : (A + (size_t)(m0 + r) * K);
        sgp[isB][h][i] = base + kbase + cl * 8;
        sdo[isB][h][i] = (u32)(isB * 32768 + r0 * 128);
      }
  auto stage = [&](int b, int isB, int h, int kt) {
    const int kk = kt < ktiles ? kt : ktiles - 1;
#pragma unroll
    for (int i = 0; i < 2; ++i)
      gld16(sgp[isB][h][i] + kk * 64, lds + b * 65536 + sdo[isB][h][i]);
  };
  auto ldA = [&](int b, int mi, int ks) {
    const int row = wm * 128 + mi * 16 + l15;
    const int ch = (ks * 4 + l4) ^ (row & 7);
    return *(const bf16x8*)(lds + b * 65536 + row * 128 + ch * 16);
  };
  auto ldB = [&](int b, int ni, int ks) {
    const int row = wn * 64 + ni * 16 + l15;
    const int ch = (ks * 4 + l4) ^ (row & 7);
    return *(const bf16x8*)(lds + b * 65536 + 32768 + row * 128 + ch * 16);
  };

  f32x4 acc[8][4] = {};
  bf16x8 aR[4][2], b0[2][2], b1[2][2];

  stage(0, 0, 0, 0); stage(0, 1, 0, 0); stage(0, 1, 1, 0); stage(0, 0, 1, 0);
  stage(1, 0, 0, 1); stage(1, 1, 1, 1); stage(1, 0, 1, 1);
  asm volatile("s_waitcnt vmcnt(6)" ::: "memory");
  __builtin_amdgcn_s_barrier();

  for (int kt = 0; kt < ktiles; kt += 2) {
#pragma unroll
    for (int mi = 0; mi < 4; ++mi) { aR[mi][0] = ldA(0, mi, 0); aR[mi][1] = ldA(0, mi, 1); }
#pragma unroll
    for (int ni = 0; ni < 2; ++ni) { b0[ni][0] = ldB(0, ni, 0); b0[ni][1] = ldB(0, ni, 1); }
    stage(1, 1, 0, kt + 1);
    __builtin_amdgcn_s_barrier();
    asm volatile("s_waitcnt lgkmcnt(0)" ::: "memory");
    __builtin_amdgcn_s_setprio(1);
#pragma unroll
    for (int mi = 0; mi < 4; ++mi)
#pragma unroll
      for (int ni = 0; ni < 2; ++ni) {
        MFMA16(acc[mi][ni], aR[mi][0], b0[ni][0]);
        MFMA16(acc[mi][ni], aR[mi][1], b0[ni][1]);
      }
    __builtin_amdgcn_s_setprio(0);
    __builtin_amdgcn_s_barrier();
#pragma unroll
    for (int ni = 0; ni < 2; ++ni) { b1[ni][0] = ldB(0, ni + 2, 0); b1[ni][1] = ldB(0, ni + 2, 1); }
    stage(0, 0, 0, kt + 2);
    __builtin_amdgcn_s_barrier();
    asm volatile("s_waitcnt lgkmcnt(0)" ::: "memory");
    __builtin_amdgcn_s_setprio(1);
#pragma unroll
    for (int mi = 0; mi < 4; ++mi)
#pragma unroll
      for (int ni = 0; ni < 2; ++ni) {
        MFMA16(acc[mi][ni + 2], aR[mi][0], b1[ni][0]);
        MFMA16(acc[mi][ni + 2], aR[mi][1], b1[ni][1]);
      }
    __builtin_amdgcn_s_setprio(0);
    __builtin_amdgcn_s_barrier();
#pragma unroll
    for (int mi = 0; mi < 4; ++mi) { aR[mi][0] = ldA(0, mi + 4, 0); aR[mi][1] = ldA(0, mi + 4, 1); }
    stage(0, 1, 1, kt + 2);
    __builtin_amdgcn_s_barrier();
    asm volatile("s_waitcnt lgkmcnt(0)" ::: "memory");
    __builtin_amdgcn_s_setprio(1);
#pragma unroll
    for (int mi = 0; mi < 4; ++mi)
#pragma unroll
      for (int ni = 0; ni < 2; ++ni) {
        MFMA16(acc[mi + 4][ni + 2], aR[mi][0], b1[ni][0]);
        MFMA16(acc[mi + 4][ni + 2], aR[mi][1], b1[ni][1]);
      }
    __builtin_amdgcn_s_setprio(0);
    __builtin_amdgcn_s_barrier();
    stage(0, 0, 1, kt + 2);
    __builtin_amdgcn_s_barrier();
    __builtin_amdgcn_s_setprio(1);
#pragma unroll
    for (int mi = 0; mi < 4; ++mi)
#pragma unroll
      for (int ni = 0; ni < 2; ++ni) {
        MFMA16(acc[mi + 4][ni], aR[mi][0], b0[ni][0]);
        MFMA16(acc[mi + 4][ni], aR[mi][1], b0[ni][1]);
      }
    __builtin_amdgcn_s_setprio(0);
    asm volatile("s_waitcnt vmcnt(6)" ::: "memory");
    __builtin_amdgcn_s_barrier();
#pragma unroll
    for (int mi = 0; mi < 4; ++mi) { aR[mi][0] = ldA(1, mi, 0); aR[mi][1] = ldA(1, mi, 1); }
#pragma unroll
    for (int ni = 0; ni < 2; ++ni) { b0[ni][0] = ldB(1, ni, 0); b0[ni][1] = ldB(1, ni, 1); }
    stage(0, 1, 0, kt + 2);
    __builtin_amdgcn_s_barrier();
    asm volatile("s_waitcnt lgkmcnt(0)" ::: "memory");
    __builtin_amdgcn_s_setprio(1);
#pragma unroll
    for (int mi = 0; mi < 4; ++mi)
#pragma unroll
      for (int ni = 0; ni < 2; ++ni) {
        MFMA16(acc[mi][ni], aR[mi][0], b0[ni][0]);
        MFMA16(acc[mi][ni], aR[mi][1], b0[ni][1]);
      }
    __builtin_amdgcn_s_setprio(0);
    __builtin_amdgcn_s_barrier();
#pragma unroll
    for (int ni = 0; ni < 2; ++ni) { b1[ni][0] = ldB(1, ni + 2, 0); b1[ni][1] = ldB(1, ni + 2, 1); }
    stage(1, 0, 0, kt + 3);
    __builtin_amdgcn_s_barrier();
    asm volatile("s_waitcnt lgkmcnt(0)" ::: "memory");
    __builtin_amdgcn_s_setprio(1);
#pragma unroll
    for (int mi = 0; mi < 4; ++mi)
#pragma unroll
      for (int ni = 0; ni < 2; ++ni) {
        MFMA16(acc[mi][ni + 2], aR[mi][0], b1[ni][0]);
        MFMA16(acc[mi][ni + 2], aR[mi][1], b1[ni][1]);
      }
    __builtin_amdgcn_s_setprio(0);
    __builtin_amdgcn_s_barrier();
#pragma unroll
    for (int mi = 0; mi < 4; ++mi) { aR[mi][0] = ldA(1, mi + 4, 0); aR[mi][1] = ldA(1, mi + 4, 1); }
    stage(1, 1, 1, kt + 3);
    __builtin_amdgcn_s_barrier();
    asm volatile("s_waitcnt lgkmcnt(0)" ::: "memory");
    __builtin_amdgcn_s_setprio(1);
#pragma unroll
    for (int mi = 0; mi < 4; ++mi)
#pragma unroll
      for (int ni = 0; ni < 2; ++ni) {
        MFMA16(acc[mi + 4][ni + 2], aR[mi][0], b1[ni][0]);
        MFMA16(acc[mi + 4][ni + 2], aR[mi][1], b1[ni][1]);
      }
    __builtin_amdgcn_s_setprio(0);
    __builtin_amdgcn_s_barrier();
    stage(1, 0, 1, kt + 3);
    __builtin_amdgcn_s_barrier();
    __builtin_amdgcn_s_setprio(1);
#pragma unroll
    for (int mi = 0; mi < 4; ++mi)
#pragma unroll
      for (int ni = 0; ni < 2; ++ni) {
        MFMA16(acc[mi + 4][ni], aR[mi][0], b0[ni][0]);
        MFMA16(acc[mi + 4][ni], aR[mi][1], b0[ni][1]);
      }
    __builtin_amdgcn_s_setprio(0);
    asm volatile("s_waitcnt vmcnt(6)" ::: "memory");
    __builtin_amdgcn_s_barrier();
  }

  u16* C16 = (u16*)Cp;
  float* Cf = (float*)Cp;
  if constexpr (EPI == 10) C16 += (size_t)blockIdx.z * ((size_t)M * N);
  if constexpr (EPI == 11) Cf += (size_t)blockIdx.z * ((size_t)M * N);
#pragma unroll
  for (int mi = 0; mi < 8; ++mi)
#pragma unroll
    for (int rr = 0; rr < 4; ++rr) {
      const int row = m0 + wm * 128 + mi * 16 + l4 * 4 + rr;
#pragma unroll
      for (int ni = 0; ni < 4; ++ni) {
        const int col = n0 + wn * 64 + ni * 16 + l15;
        const size_t idx = (size_t)row * N + col;
        const float v = acc[mi][ni][rr];
        if constexpr (EPI == 11) {
          Cf[idx] = v;
        } else if constexpr (EPI == 3) {
          const float g = bf2f(aux[idx]);
          C16[idx] = f2bf(v * g / (1.f + __expf(-g)));
        } else if constexpr (EPI == 4) {
          C16[idx] = f2bf(slotw[row] * v);
        } else {
          C16[idx] = f2bf(v);
        }
      }
    }
}

// ---------------- GEMM_GU_M: merged shared+expert fused gate+up, 8-phase ----------------
// grid (86, 32): y<8 -> shared (688 blocks, XCD swizzle); y>=8 -> expert tiles (x<16).
__global__ __launch_bounds__(512, 2) void gemm_gu_m(
    const u16* __restrict__ A,
    const u16* __restrict__ Bsg, const u16* __restrict__ Bsu, u16* __restrict__ G,
    const u16* __restrict__ Beg, const u16* __restrict__ Beu, u16* __restrict__ ACT,
    const int* __restrict__ slot_tok, const int* __restrict__ tiletab, int K) {
  __shared__ char lds[131072];
  const int t = threadIdx.x, w = t >> 6, l = t & 63;
  int m0, nt, LDC;
  const u16 *Bg, *Bu;
  u16* dst;
  bool expertp;
  if ((int)blockIdx.y < 8) {
    expertp = false;
    int wg = blockIdx.y * 86 + blockIdx.x;        // nwg = 688, %8 == 0
    wg = (wg & 7) * 86 + (wg >> 3);               // XCD swizzle (bijective)
    m0 = (wg & 7) * 256;
    nt = wg >> 3;
    Bg = Bsg; Bu = Bsu; dst = G; LDC = FSH;
  } else {
    expertp = true;
    if ((int)blockIdx.x >= 16) return;
    const int ntil = tiletab[0];
    const int ty = blockIdx.y - 8;
    if (ty >= ntil) return;
    const int e = tiletab[1 + ty * 2];
    m0 = tiletab[2 + ty * 2];
    nt = blockIdx.x;
    const size_t boff = (size_t)e * 2048 * K;
    Bg = Beg + boff; Bu = Beu + boff; dst = ACT; LDC = 2048;
  }
  const int ktiles = K >> 6;
  const int wm = w >> 2, wn = w & 3;
  const int l15 = l & 15, l4 = l >> 4;
  const int sro = l >> 3, sc = l & 7;

  const u16* sga[2][2]; u32 sda[2][2];
#pragma unroll
  for (int h = 0; h < 2; ++h)
#pragma unroll
    for (int i = 0; i < 2; ++i) {
      const int q = i * 8 + w;
      const int r0 = ((q & 8) << 4) + h * 64 + (q & 7) * 8;
      const int r = r0 + sro;
      const int cl = sc ^ (r & 7);
      const size_t arow = expertp ? (size_t)slot_tok[m0 + r] : (size_t)(m0 + r);
      sga[h][i] = A + arow * K + cl * 8;
      sda[h][i] = (u32)(r0 * 128);
    }
  const u16* sgb[2][2]; u32 sdb[2][2];
#pragma unroll
  for (int mat = 0; mat < 2; ++mat)
#pragma unroll
    for (int i = 0; i < 2; ++i) {
      const int q = i * 8 + w;
      const int r0 = q * 8;
      const int r = r0 + sro;
      const int cl = sc ^ (r & 7);
      const u16* B = mat ? Bu : Bg;
      sgb[mat][i] = B + (size_t)(nt * 128 + r) * K + cl * 8;
      sdb[mat][i] = (u32)(32768 + mat * 16384 + r0 * 128);
    }
  auto stgA = [&](int b, int h, int kt) {
    const int kk = kt < ktiles ? kt : ktiles - 1;
#pragma unroll
    for (int i = 0; i < 2; ++i) gld16(sga[h][i] + kk * 64, lds + b * 65536 + sda[h][i]);
  };
  auto stgB = [&](int b, int mat, int kt) {
    const int kk = kt < ktiles ? kt : ktiles - 1;
#pragma unroll
    for (int i = 0; i < 2; ++i) gld16(sgb[mat][i] + kk * 64, lds + b * 65536 + sdb[mat][i]);
  };
  auto ldA = [&](int b, int mi, int ks) {
    const int row = wm * 128 + mi * 16 + l15;
    const int ch = (ks * 4 + l4) ^ (row & 7);
    return *(const bf16x8*)(lds + b * 65536 + row * 128 + ch * 16);
  };
  auto ldB = [&](int b, int mat, int ni, int ks) {
    const int row = wn * 32 + ni * 16 + l15;
    const int ch = (ks * 4 + l4) ^ (row & 7);
    return *(const bf16x8*)(lds + b * 65536 + 32768 + mat * 16384 + row * 128 + ch * 16);
  };

  f32x4 accg[8][2] = {}, accu[8][2] = {};
  bf16x8 aR[4][2], bg[2][2], bu[2][2];

  stgA(0, 0, 0); stgB(0, 0, 0); stgB(0, 1, 0); stgA(0, 1, 0);
  stgA(1, 0, 1); stgB(1, 1, 1); stgA(1, 1, 1);
  asm volatile("s_waitcnt vmcnt(6)" ::: "memory");
  __builtin_amdgcn_s_barrier();

  for (int kt = 0; kt < ktiles; kt += 2) {
#pragma unroll
    for (int mi = 0; mi < 4; ++mi) { aR[mi][0] = ldA(0, mi, 0); aR[mi][1] = ldA(0, mi, 1); }
#pragma unroll
    for (int ni = 0; ni < 2; ++ni) { bg[ni][0] = ldB(0, 0, ni, 0); bg[ni][1] = ldB(0, 0, ni, 1); }
    stgB(1, 0, kt + 1);
    __builtin_amdgcn_s_barrier();
    asm volatile("s_waitcnt lgkmcnt(0)" ::: "memory");
    __builtin_amdgcn_s_setprio(1);
#pragma unroll
    for (int mi = 0; mi < 4; ++mi)
#pragma unroll
      for (int ni = 0; ni < 2; ++ni) {
        MFMA16(accg[mi][ni], aR[mi][0], bg[ni][0]);
        MFMA16(accg[mi][ni], aR[mi][1], bg[ni][1]);
      }
    __builtin_amdgcn_s_setprio(0);
    __builtin_amdgcn_s_barrier();
#pragma unroll
    for (int ni = 0; ni < 2; ++ni) { bu[ni][0] = ldB(0, 1, ni, 0); bu[ni][1] = ldB(0, 1, ni, 1); }
    stgA(0, 0, kt + 2);
    __builtin_amdgcn_s_barrier();
    asm volatile("s_waitcnt lgkmcnt(0)" ::: "memory");
    __builtin_amdgcn_s_setprio(1);
#pragma unroll
    for (int mi = 0; mi < 4; ++mi)
#pragma unroll
      for (int ni = 0; ni < 2; ++ni) {
        MFMA16(accu[mi][ni], aR[mi][0], bu[ni][0]);
        MFMA16(accu[mi][ni], aR[mi][1], bu[ni][1]);
      }
    __builtin_amdgcn_s_setprio(0);
    __builtin_amdgcn_s_barrier();
#pragma unroll
    for (int mi = 0; mi < 4; ++mi) { aR[mi][0] = ldA(0, mi + 4, 0); aR[mi][1] = ldA(0, mi + 4, 1); }
    stgB(0, 1, kt + 2);
    __builtin_amdgcn_s_barrier();
    asm volatile("s_waitcnt lgkmcnt(0)" ::: "memory");
    __builtin_amdgcn_s_setprio(1);
#pragma unroll
    for (int mi = 0; mi < 4; ++mi)
#pragma unroll
      for (int ni = 0; ni < 2; ++ni) {
        MFMA16(accu[mi + 4][ni], aR[mi][0], bu[ni][0]);
        MFMA16(accu[mi + 4][ni], aR[mi][1], bu[ni][1]);
      }
    __builtin_amdgcn_s_setprio(0);
    __builtin_amdgcn_s_barrier();
    stgA(0, 1, kt + 2);
    __builtin_amdgcn_s_barrier();
    __builtin_amdgcn_s_setprio(1);
#pragma unroll
    for (int mi = 0; mi < 4; ++mi)
#pragma unroll
      for (int ni = 0; ni < 2; ++ni) {
        MFMA16(accg[mi + 4][ni], aR[mi][0], bg[ni][0]);
        MFMA16(accg[mi + 4][ni], aR[mi][1], bg[ni][1]);
      }
    __builtin_amdgcn_s_setprio(0);
    asm volatile("s_waitcnt vmcnt(6)" ::: "memory");
    __builtin_amdgcn_s_barrier();
#pragma unroll
    for (int mi = 0; mi < 4; ++mi) { aR[mi][0] = ldA(1, mi, 0); aR[mi][1] = ldA(1, mi, 1); }
#pragma unroll
    for (int ni = 0; ni < 2; ++ni) { bg[ni][0] = ldB(1, 0, ni, 0); bg[ni][1] = ldB(1, 0, ni, 1); }
    stgB(0, 0, kt + 2);
    __builtin_amdgcn_s_barrier();
    asm volatile("s_waitcnt lgkmcnt(0)" ::: "memory");
    __builtin_amdgcn_s_setprio(1);
#pragma unroll
    for (int mi = 0; mi < 4; ++mi)
#pragma unroll
      for (int ni = 0; ni < 2; ++ni) {
        MFMA16(accg[mi][ni], aR[mi][0], bg[ni][0]);
        MFMA16(accg[mi][ni], aR[mi][1], bg[ni][1]);
      }
    __builtin_amdgcn_s_setprio(0);
    __builtin_amdgcn_s_barrier();
#pragma unroll
    for (int ni = 0; ni < 2; ++ni) { bu[ni][0] = ldB(1, 1, ni, 0); bu[ni][1] = ldB(1, 1, ni, 1); }
    stgA(1, 0, kt + 3);
    __builtin_amdgcn_s_barrier();
    asm volatile("s_waitcnt lgkmcnt(0)" ::: "memory");
    __builtin_amdgcn_s_setprio(1);
#pragma unroll
    for (int mi = 0; mi < 4; ++mi)
#pragma unroll
      for (int ni = 0; ni < 2; ++ni) {
        MFMA16(accu[mi][ni], aR[mi][0], bu[ni][0]);
        MFMA16(accu[mi][ni], aR[mi][1], bu[ni][1]);
      }
    __builtin_amdgcn_s_setprio(0);
    __builtin_amdgcn_s_barrier();
#pragma unroll
    for (int mi = 0; mi < 4; ++mi) { aR[mi][0] = ldA(1, mi + 4, 0); aR[mi][1] = ldA(1, mi + 4, 1); }
    stgB(1, 1, kt + 3);
    __builtin_amdgcn_s_barrier();
    asm volatile("s_waitcnt lgkmcnt(0)" ::: "memory");
    __builtin_amdgcn_s_setprio(1);
#pragma unroll
    for (int mi = 0; mi < 4; ++mi)
#pragma unroll
      for (int ni = 0; ni < 2; ++ni) {
        MFMA16(accu[mi + 4][ni], aR[mi][0], bu[ni][0]);
        MFMA16(accu[mi + 4][ni], aR[mi][1], bu[ni][1]);
      }
    __builtin_amdgcn_s_setprio(0);
    __builtin_amdgcn_s_barrier();
    stgA(1, 1, kt + 3);
    __builtin_amdgcn_s_barrier();
    __builtin_amdgcn_s_setprio(1);
#pragma unroll
    for (int mi = 0; mi < 4; ++mi)
#pragma unroll
      for (int ni = 0; ni < 2; ++ni) {
        MFMA16(accg[mi + 4][ni], aR[mi][0], bg[ni][0]);
        MFMA16(accg[mi + 4][ni], aR[mi][1], bg[ni][1]);
      }
    __builtin_amdgcn_s_setprio(0);
    asm volatile("s_waitcnt vmcnt(6)" ::: "memory");
    __builtin_amdgcn_s_barrier();
  }

#pragma unroll
  for (int mi = 0; mi < 8; ++mi)
#pragma unroll
    for (int rr = 0; rr < 4; ++rr) {
      const int row = m0 + wm * 128 + mi * 16 + l4 * 4 + rr;
#pragma unroll
      for (int ni = 0; ni < 2; ++ni) {
        const int col = nt * 128 + wn * 32 + ni * 16 + l15;
        const float g = accg[mi][ni][rr];
        const float u = accu[mi][ni][rr];
        dst[(size_t)row * LDC + col] = f2bf(u * g / (1.f + __expf(-g)));
      }
    }
}

// ---------------- split-K reduce (bf16 parts x4): dst = base + sum ----------------
__global__ __launch_bounds__(256) void redbf_k(float* __restrict__ dst,
                                               const float* __restrict__ base,
                                               const u16* __restrict__ parts) {
  const int i = blockIdx.x * 256 + threadIdx.x;
  float s[8];
  const float* bp = base + (size_t)i * 8;
#pragma unroll
  for (int j = 0; j < 8; ++j) s[j] = bp[j];
#pragma unroll
  for (int p = 0; p < 4; ++p) {
    u16x8 v = ((const u16x8*)parts)[(size_t)p * 524288 + i];
#pragma unroll
    for (int j = 0; j < 8; ++j) s[j] += bf2f(v[j]);
  }
  float* dp = dst + (size_t)i * 8;
#pragma unroll
  for (int j = 0; j < 8; ++j) dp[j] = s[j];
}

// ---------------- RoPE from bf16 split-K parts + pack Q/K/V + emit new_k/new_v ----------
__global__ __launch_bounds__(256) void rope_k(
    const u16* __restrict__ p0, const u16* __restrict__ p1,
    const float* __restrict__ cosb, const float* __restrict__ sinb,
    const float* __restrict__ bq, const float* __restrict__ bk, const float* __restrict__ bv,
    u16* __restrict__ QR, u16* __restrict__ KR, u16* __restrict__ VB,
    float* __restrict__ NK, float* __restrict__ NV) {
  const int s = blockIdx.x, b = blockIdx.y, t = threadIdx.x;
  const size_t tok = (size_t)b * 1024 + s;
  const u16* r0 = p0 + tok * 3072;
  const u16* r1 = p1 + tok * 3072;
  const float* cr = cosb + s * 128;
  const float* sr = sinb + s * 128;
  for (int i = t; i < 1024; i += 256) {
    const int h = i >> 6, d = i & 63;
    const float v1 = bf2f(r0[h * 128 + d]) + bf2f(r1[h * 128 + d]) + bq[h * 128 + d];
    const float v2 = bf2f(r0[h * 128 + d + 64]) + bf2f(r1[h * 128 + d + 64]) + bq[h * 128 + d + 64];
    const float o1 = v1 * cr[d] - v2 * sr[d];
    const float o2 = v2 * cr[d + 64] + v1 * sr[d + 64];
    const size_t qb = (((size_t)(b * 16 + h)) * 1024 + s) * 128;
    QR[qb + d] = f2bf(o1);
    QR[qb + d + 64] = f2bf(o2);
  }
  {
    const int h = t >> 6, d = t & 63;
    const float v1 = bf2f(r0[2048 + h * 128 + d]) + bf2f(r1[2048 + h * 128 + d]) + bk[h * 128 + d];
    const float v2 = bf2f(r0[2048 + h * 128 + d + 64]) + bf2f(r1[2048 + h * 128 + d + 64]) + bk[h * 128 + d + 64];
    const float o1 = v1 * cr[d] - v2 * sr[d];
    const float o2 = v2 * cr[d + 64] + v1 * sr[d + 64];
    const size_t kb = (((size_t)(b * 4 + h)) * 1024 + s) * 128;
    KR[kb + d] = f2bf(o1);
    KR[kb + d + 64] = f2bf(o2);
    const size_t ob = tok * 2048;
#pragma unroll
    for (int rep = 0; rep < 4; ++rep) {
      NK[ob + (h * 4 + rep) * 128 + d] = o1;
      NK[ob + (h * 4 + rep) * 128 + d + 64] = o2;
    }
  }
  for (int i = t; i < 512; i += 256) {
    const int h = i >> 7, d = i & 127;
    const float v = bf2f(r0[2560 + i]) + bf2f(r1[2560 + i]) + bv[i];
    VB[(((size_t)(b * 4 + h)) * 1024 + s) * 128 + d] = f2bf(v);
    const size_t ob = tok * 2048;
#pragma unroll
    for (int rep = 0; rep < 4; ++rep) NV[ob + (h * 4 + rep) * 128 + d] = v;
  }
}

// ---------------- Flash attention + fused wd transpose (z==2 plane) ----------------
__global__ __launch_bounds__(256) void attn_k(const u16* __restrict__ Q,
                                              const u16* __restrict__ Kc,
                                              const u16* __restrict__ Vc,
                                              u16* __restrict__ O,
                                              const float* __restrict__ wdsrc,
                                              u16* __restrict__ wtd) {
  __shared__ u16 Ks[64 * 128];
  __shared__ u16 Vt[128 * 66];
  __shared__ u16 Ps[4][16 * 68];
  const int t = threadIdx.x, w = t >> 6, l = t & 63;
  if (blockIdx.z == 2) {
    u16* tile = Ks;  // 64*80 <= 64*128
    const int bi = blockIdx.y * 16 + blockIdx.x;
#pragma unroll 1
    for (int i = 0; i < 32; ++i) {
      const int ti = bi * 32 + i;
      const int e = ti >> 10, rem = ti & 1023;
      ttile(wdsrc + (size_t)e * 4194304, wtd + (size_t)e * 4194304,
            2048, 2048, (rem & 31) * 64, (rem >> 5) * 64, tile, t);
      __syncthreads();
    }
    return;
  }
  const int qt = blockIdx.x, h = blockIdx.y, b = blockIdx.z;
  const int kvh = h >> 2;
  const int l15 = l & 15, l4 = l >> 4;
  bf16x8 qf[4];
  {
    const u16* qb = Q + (((size_t)(b * 16 + h)) * 1024 + qt * 64 + w * 16 + l15) * 128 + l4 * 8;
#pragma unroll
    for (int c = 0; c < 4; ++c) qf[c] = *(const bf16x8*)(qb + c * 32);
  }
  float m_run[4] = {-1e30f, -1e30f, -1e30f, -1e30f};
  float l_run[4] = {0.f, 0.f, 0.f, 0.f};
  f32x4 accO[8] = {};
  const size_t kvbase = ((size_t)(b * 4 + kvh)) * 1024 * 128;
  const int ntiles = qt + 1;
  for (int kt = 0; kt < ntiles; ++kt) {
    __syncthreads();
    {
      const int key = t >> 2;
      const u16* kg = Kc + kvbase + (size_t)(kt * 64 + key) * 128;
      const u16* vg = Vc + kvbase + (size_t)(kt * 64 + key) * 128;
      const int sw = (key & 7) << 4;
#pragma unroll
      for (int p = 0; p < 4; ++p) {
        const int ch = (t & 3) * 4 + p;
        *(u16x8*)((char*)Ks + key * 256 + ((ch * 16) ^ sw)) = *(const u16x8*)(kg + ch * 8);
        const int d0 = ch * 8;
        u16x8 vv = *(const u16x8*)(vg + d0);
#pragma unroll
        for (int j = 0; j < 8; ++j) Vt[(d0 + j) * 66 + key] = vv[j];
      }
    }
    __syncthreads();
    f32x4 sf[4] = {};
    __builtin_amdgcn_s_setprio(1);
#pragma unroll
    for (int nf = 0; nf < 4; ++nf) {
      const int keyl = nf * 16 + l15;
      const int sw = (keyl & 7) << 4;
      const char* kbase = (const char*)Ks + keyl * 256;
#pragma unroll
      for (int c = 0; c < 4; ++c) {
        bf16x8 kf = *(const bf16x8*)(kbase + ((c * 64 + l4 * 16) ^ sw));
        sf[nf] = __builtin_amdgcn_mfma_f32_16x16x32_bf16(qf[c], kf, sf[nf], 0, 0, 0);
      }
    }
    __builtin_amdgcn_s_setprio(0);
    const int qg0 = qt * 64 + w * 16 + l4 * 4;
    float alpha[4];
#pragma unroll
    for (int r = 0; r < 4; ++r) {
      const int qg = qg0 + r;
      float tm = -1e30f;
#pragma unroll
      for (int nf = 0; nf < 4; ++nf) {
        const int kg = kt * 64 + nf * 16 + l15;
        float sv = sf[nf][r] * 0.088388347648318447f;
        sv = (kg <= qg) ? sv : -1e30f;
        sf[nf][r] = sv;
        tm = fmaxf(tm, sv);
      }
#pragma unroll
      for (int mm = 1; mm < 16; mm <<= 1) tm = fmaxf(tm, __shfl_xor(tm, mm));
      const float mn = fmaxf(m_run[r], tm);
      alpha[r] = __expf(m_run[r] - mn);
      m_run[r] = mn;
      float rs = 0.f;
#pragma unroll
      for (int nf = 0; nf < 4; ++nf) {
        const float p = __expf(sf[nf][r] - mn);
        sf[nf][r] = p;
        rs += p;
      }
#pragma unroll
      for (int mm = 1; mm < 16; mm <<= 1) rs += __shfl_xor(rs, mm);
      l_run[r] = l_run[r] * alpha[r] + rs;
    }
#pragma unroll
    for (int nf = 0; nf < 8; ++nf)
#pragma unroll
      for (int r = 0; r < 4; ++r) accO[nf][r] *= alpha[r];
#pragma unroll
    for (int nf = 0; nf < 4; ++nf)
#pragma unroll
      for (int r = 0; r < 4; ++r)
        Ps[w][(l4 * 4 + r) * 68 + nf * 16 + l15] = f2bf(sf[nf][r]);
    __syncthreads();
    __builtin_amdgcn_s_setprio(1);
#pragma unroll
    for (int kc = 0; kc < 2; ++kc) {
      const u16* pb = &Ps[w][0] + l15 * 68 + kc * 32 + l4 * 8;
      union { u16x4 q[2]; bf16x8 v; } pu;
      pu.q[0] = *(const u16x4*)pb;
      pu.q[1] = *(const u16x4*)(pb + 4);
#pragma unroll
      for (int nf = 0; nf < 8; ++nf) {
        const int dd = nf * 16 + l15;
        const u16* vp = &Vt[0] + dd * 66 + kc * 32 + l4 * 8;
        union { u32 u[4]; bf16x8 v; } vu;
        vu.u[0] = *(const u32*)(vp);
        vu.u[1] = *(const u32*)(vp + 2);
        vu.u[2] = *(const u32*)(vp + 4);
        vu.u[3] = *(const u32*)(vp + 6);
        accO[nf] = __builtin_amdgcn_mfma_f32_16x16x32_bf16(pu.v, vu.v, accO[nf], 0, 0, 0);
      }
    }
    __builtin_amdgcn_s_setprio(0);
  }
  const int qg0 = qt * 64 + w * 16 + l4 * 4;
#pragma unroll
  for (int nf = 0; nf < 8; ++nf) {
    const int dd = nf * 16 + l15;
#pragma unroll
    for (int r = 0; r < 4; ++r) {
      const float o = accO[nf][r] / l_run[r];
      O[((size_t)(b * 1024 + qg0 + r)) * 2048 + h * 128 + dd] = f2bf(o);
    }
  }
}

// ---------------- Fused residual+rmsnorm+router + fused wsd transpose (tail blocks) ----
__global__ __launch_bounds__(256) void fuserouter_k(
    const float* __restrict__ x, const float* __restrict__ parts,
    const float* __restrict__ wn, const float* __restrict__ rw,
    float* __restrict__ X2, u16* __restrict__ HN,
    int* __restrict__ topi2, float* __restrict__ topw2, float* __restrict__ probs,
    const float* __restrict__ wsdsrc, u16* __restrict__ wtsd) {
  __shared__ u16 tile[64 * 80];
  __shared__ float red[4];
  __shared__ float racc[32];
  const int t = threadIdx.x, w = t >> 6;
  if ((int)blockIdx.x >= TT) {
    const int bi = blockIdx.x - TT;   // 344 blocks x 16 tiles = 5504
#pragma unroll 1
    for (int i = 0; i < 16; ++i) {
      const int ti = bi * 16 + i;
      ttile(wsdsrc, wtsd, FSH, 2048, (ti & 31) * 64, (ti >> 5) * 64, tile, t);
      __syncthreads();
    }
    return;
  }
  const int tok = blockIdx.x;
  const size_t base = (size_t)tok * DD + t * 8;
  float v[8];
  {
    float4 a = *(const float4*)(x + base);
    float4 b = *(const float4*)(x + base + 4);
    v[0] = a.x; v[1] = a.y; v[2] = a.z; v[3] = a.w;
    v[4] = b.x; v[5] = b.y; v[6] = b.z; v[7] = b.w;
  }
#pragma unroll
  for (int p = 0; p < 4; ++p) {
    const float* pr = parts + (size_t)p * (TT * DD) + base;
    float4 a = *(const float4*)(pr);
    float4 b = *(const float4*)(pr + 4);
    v[0] += a.x; v[1] += a.y; v[2] += a.z; v[3] += a.w;
    v[4] += b.x; v[5] += b.y; v[6] += b.z; v[7] += b.w;
  }
  *(float4*)(X2 + base) = make_float4(v[0], v[1], v[2], v[3]);
  *(float4*)(X2 + base + 4) = make_float4(v[4], v[5], v[6], v[7]);
  float ss = 0.f;
#pragma unroll
  for (int j = 0; j < 8; ++j) ss += v[j] * v[j];
#pragma unroll
  for (int m = 1; m < 64; m <<= 1) ss += __shfl_xor(ss, m);
  if ((t & 63) == 0) red[w] = ss;
  __syncthreads();
  const float sc = rsqrtf((red[0] + red[1] + red[2] + red[3]) * (1.f / DD) + 1e-6f);
  float hn[8];
  u16x8 o;
#pragma unroll
  for (int j = 0; j < 8; ++j) {
    hn[j] = v[j] * sc * wn[t * 8 + j];
    o[j] = f2bf(hn[j]);
  }
  *(u16x8*)(HN + base) = o;
  float acc[8] = {};
#pragma unroll
  for (int j = 0; j < 8; ++j) {
    const int d = t * 8 + j;
    float4 r0 = *(const float4*)(rw + d * 8);
    float4 r1 = *(const float4*)(rw + d * 8 + 4);
    acc[0] += hn[j] * r0.x; acc[1] += hn[j] * r0.y; acc[2] += hn[j] * r0.z; acc[3] += hn[j] * r0.w;
    acc[4] += hn[j] * r1.x; acc[5] += hn[j] * r1.y; acc[6] += hn[j] * r1.z; acc[7] += hn[j] * r1.w;
  }
#pragma unroll
  for (int m = 1; m < 64; m <<= 1)
#pragma unroll
    for (int e = 0; e < 8; ++e) acc[e] += __shfl_xor(acc[e], m);
  if ((t & 63) == 0)
#pragma unroll
    for (int e = 0; e < 8; ++e) racc[w * 8 + e] = acc[e];
  __syncthreads();
  if (t == 0) {
    float lg[8];
#pragma unroll
    for (int e = 0; e < 8; ++e) lg[e] = racc[e] + racc[8 + e] + racc[16 + e] + racc[24 + e];
    float mx = lg[0];
#pragma unroll
    for (int e = 1; e < 8; ++e) mx = fmaxf(mx, lg[e]);
    float p[8], sum = 0.f;
#pragma unroll
    for (int e = 0; e < 8; ++e) { p[e] = __expf(lg[e] - mx); sum += p[e]; }
    const float inv = 1.f / sum;
#pragma unroll
    for (int e = 0; e < 8; ++e) p[e] *= inv;
    *(float4*)(probs + tok * 8) = make_float4(p[0], p[1], p[2], p[3]);
    *(float4*)(probs + tok * 8 + 4) = make_float4(p[4], p[5], p[6], p[7]);
    int e0 = 0; float v0 = p[0];
#pragma unroll
    for (int e = 1; e < 8; ++e) if (p[e] > v0) { v0 = p[e]; e0 = e; }
    int e1 = (e0 == 0) ? 1 : 0; float v1 = p[e1];
#pragma unroll
    for (int e = 0; e < 8; ++e) if (e != e0 && p[e] > v1) { v1 = p[e]; e1 = e; }
    const float wsum = v0 + v1;
    topi2[tok * 2] = e0; topi2[tok * 2 + 1] = e1;
    topw2[tok * 2] = v0 / wsum; topw2[tok * 2 + 1] = v1 / wsum;
  }
}

__global__ __launch_bounds__(256) void zero_k(int* __restrict__ slot_tok,
                                              float* __restrict__ slot_w) {
  const int i = blockIdx.x * 256 + threadIdx.x;
  if (i < 6144) { slot_tok[i] = 0; slot_w[i] = 0.f; }
}

// ---------------- scan2: counts+pmean reduction + 256-row tile table ----------------
__global__ __launch_bounds__(256) void scan2_k(const int* __restrict__ topi2,
                                               const float* __restrict__ probs,
                                               int* __restrict__ cursors,
                                               int* __restrict__ tiletab,
                                               float* __restrict__ auxout) {
  const int t = threadIdx.x, w = t >> 6, l = t & 63;
  __shared__ int cnt[8];
  __shared__ float wsum[4][8];
  if (t < 8) cnt[t] = 0;
  __syncthreads();
  float ps[8] = {};
  for (int i = t; i < 2048; i += 256) {
    atomicAdd(&cnt[topi2[i * 2]], 1);
    atomicAdd(&cnt[topi2[i * 2 + 1]], 1);
    float4 a = *(const float4*)(probs + i * 8);
    float4 b = *(const float4*)(probs + i * 8 + 4);
    ps[0] += a.x; ps[1] += a.y; ps[2] += a.z; ps[3] += a.w;
    ps[4] += b.x; ps[5] += b.y; ps[6] += b.z; ps[7] += b.w;
  }
#pragma unroll
  for (int m = 1; m < 64; m <<= 1)
#pragma unroll
    for (int e = 0; e < 8; ++e) ps[e] += __shfl_xor(ps[e], m);
  if (l == 0)
#pragma unroll
    for (int e = 0; e < 8; ++e) wsum[w][e] = ps[e];
  __syncthreads();
  if (t == 0) {
    int off = 0, nt = 0;
    float aux = 0.f;
    for (int e = 0; e < 8; ++e) {
      cursors[e] = off;
      const int c = cnt[e];
      const int nte = (c + 255) >> 8;
      for (int i = 0; i < nte; ++i) {
        tiletab[1 + nt * 2] = e;
        tiletab[2 + nt * 2] = off + i * 256;
        ++nt;
      }
      off += nte * 256;
      const float pm = (wsum[0][e] + wsum[1][e] + wsum[2][e] + wsum[3][e]) * (1.f / 2048.f);
      aux += ((float)c * (1.f / 4096.f)) * pm;
    }
    tiletab[0] = nt;
    *auxout = 8.f * aux;
  }
}

// ---------------- assign: LDS-local rank, 8 global atomics per block ----------------
__global__ __launch_bounds__(256) void assign_k(const int* __restrict__ topi2,
                                                const float* __restrict__ topw2,
                                                int* __restrict__ cursors,
                                                int* __restrict__ slot_tok,
                                                float* __restrict__ slot_w,
                                                int* __restrict__ tok_slot) {
  __shared__ int lcnt[8];
  __shared__ int base[8];
  const int t = threadIdx.x;
  const int tok = blockIdx.x * 256 + t;
  if (t < 8) lcnt[t] = 0;
  __syncthreads();
  int e[2], lr[2];
#pragma unroll
  for (int j = 0; j < 2; ++j) {
    e[j] = topi2[tok * 2 + j];
    lr[j] = atomicAdd(&lcnt[e[j]], 1);
  }
  __syncthreads();
  if (t < 8) base[t] = atomicAdd(&cursors[t], lcnt[t]);
  __syncthreads();
#pragma unroll
  for (int j = 0; j < 2; ++j) {
    const int s = base[e[j]] + lr[j];
    slot_tok[s] = tok;
    slot_w[s] = topw2[tok * 2 + j];
    tok_slot[tok * 2 + j] = s;
  }
}

// ---------------- final: out += routed[s0] + routed[s1] ----------------
__global__ __launch_bounds__(256) void final_k(float* __restrict__ out,
                                               const u16* __restrict__ routed,
                                               const int* __restrict__ tok_slot) {
  const int tok = blockIdx.x, t = threadIdx.x;
  const int s0 = tok_slot[tok * 2], s1 = tok_slot[tok * 2 + 1];
  u16x8 a = ((const u16x8*)(routed + (size_t)s0 * DD))[t];
  u16x8 b = ((const u16x8*)(routed + (size_t)s1 * DD))[t];
  float* o = out + (size_t)tok * DD + t * 8;
  float4 o0 = *(const float4*)o;
  float4 o1 = *(const float4*)(o + 4);
  o0.x += bf2f(a[0]) + bf2f(b[0]); o0.y += bf2f(a[1]) + bf2f(b[1]);
  o0.z += bf2f(a[2]) + bf2f(b[2]); o0.w += bf2f(a[3]) + bf2f(b[3]);
  o1.x += bf2f(a[4]) + bf2f(b[4]); o1.y += bf2f(a[5]) + bf2f(b[5]);
  o1.z += bf2f(a[6]) + bf2f(b[6]); o1.w += bf2f(a[7]) + bf2f(b[7]);
  *(float4*)o = o0;
  *(float4*)(o + 4) = o1;
}

extern "C" void kernel_launch(void* const* d_in, const int* in_sizes, int n_in,
                              void* d_out, int out_size, void* d_ws, size_t ws_size,
                              hipStream_t stream) {
  (void)in_sizes; (void)n_in; (void)out_size; (void)ws_size;
  const float* x    = (const float*)d_in[0];
  const float* rc   = (const float*)d_in[1];
  const float* rs   = (const float*)d_in[2];
  const float* anw  = (const float*)d_in[3];
  const float* fnw  = (const float*)d_in[4];
  const float* wq   = (const float*)d_in[5];
  const float* bq   = (const float*)d_in[6];
  const float* wk   = (const float*)d_in[7];
  const float* bk   = (const float*)d_in[8];
  const float* wv   = (const float*)d_in[9];
  const float* bv   = (const float*)d_in[10];
  const float* wo   = (const float*)d_in[11];
  const float* rw   = (const float*)d_in[12];
  const float* wg   = (const float*)d_in[13];
  const float* wu   = (const float*)d_in[14];
  const float* wd   = (const float*)d_in[15];
  const float* wsg  = (const float*)d_in[16];
  const float* wsu  = (const float*)d_in[17];
  const float* wsd  = (const float*)d_in[18];

  // Workspace ~733 MB; dedicated regions, no aliasing.
  const size_t MB = (size_t)1 << 20;
  char* ws = (char*)d_ws;
  float* X2     = (float*)(ws + 0);          // 16
  u16*   HN     = (u16*)(ws + 16 * MB);      // 8
  char*  SM     = ws + 24 * MB;              // 1
  u16*   H      = (u16*)(ws + 25 * MB);      // 8
  u16*   WTQ    = (u16*)(ws + 33 * MB);      // 12
  u16*   PARTSQ = (u16*)(ws + 46 * MB);      // 26
  u16*   QR     = (u16*)(ws + 72 * MB);      // 8
  u16*   KR     = (u16*)(ws + 80 * MB);      // 2
  u16*   VBb    = (u16*)(ws + 82 * MB);      // 2
  u16*   ATTNO  = (u16*)(ws + 84 * MB);      // 8
  u16*   WTO    = (u16*)(ws + 92 * MB);      // 8
  float* PARTSW = (float*)(ws + 100 * MB);   // 64
  u16*   WTSg   = (u16*)(ws + 164 * MB);     // 44
  u16*   WTSu   = (u16*)(ws + 208 * MB);     // 44
  u16*   G      = (u16*)(ws + 252 * MB);     // 44
  u16*   WTSd   = (u16*)(ws + 296 * MB);     // 44
  u16*   PARTSD = (u16*)(ws + 340 * MB);     // 32
  u16*   WTEg   = (u16*)(ws + 372 * MB);     // 64
  u16*   WTEu   = (u16*)(ws + 436 * MB);     // 64
  u16*   WTEd   = (u16*)(ws + 500 * MB);     // 64
  u16*   ACT    = (u16*)(ws + 564 * MB);     // 24
  u16*   ROUTED = (u16*)(ws + 588 * MB);     // 24

  int*   CURS  = (int*)(SM + 256);
  int*   TILT  = (int*)(SM + 512);
  int*   TOPI  = (int*)(SM + 4096);
  float* TOPW  = (float*)(SM + 40960);
  int*   STOK  = (int*)(SM + 73728);
  float* SW    = (float*)(SM + 98304);
  int*   TSLOT = (int*)(SM + 131072);
  float* PROBS = (float*)(SM + 163840);

  float* out  = (float*)d_out;
  float* NK   = out + 4194304;
  float* NV   = out + 2 * 4194304;
  float* AUXO = out + 3 * 4194304;

  const dim3 b256(256);
  const dim3 b512(512);

  // P1: attn rmsnorm + QKV projection (gemm8 split-K x2, bf16 parts)
  rmsnorm_k<<<TT, b256, 0, stream>>>(x, anw, H);
  transp_k<<<dim3(32, 32, 1), b256, 0, stream>>>(wq, WTQ, 2048, 2048);
  transp_k<<<dim3(8, 32, 1), b256, 0, stream>>>(wk, WTQ + (size_t)2048 * 2048, 2048, 512);
  transp_k<<<dim3(8, 32, 1), b256, 0, stream>>>(wv, WTQ + (size_t)2560 * 2048, 2048, 512);
  gemm8<10, true, false><<<dim3(12, 8, 2), b512, 0, stream>>>(
      H, WTQ, PARTSQ, nullptr, nullptr, nullptr, TT, 3072, 2048, 1024);
  // P2: rope + attention (attn hosts fused wd transpose on z==2 plane)
  rope_k<<<dim3(1024, 2), b256, 0, stream>>>(PARTSQ, PARTSQ + (size_t)TT * 3072, rc, rs,
                                             bq, bk, bv, QR, KR, VBb, NK, NV);
  attn_k<<<dim3(16, 16, 3), b256, 0, stream>>>(QR, KR, VBb, ATTNO, wd, WTEd);
  // P3: wo projection (gemm8 split-K x4, f32 parts)
  transp_k<<<dim3(32, 32, 1), b256, 0, stream>>>(wo, WTO, 2048, 2048);
  gemm8<11, true, false><<<dim3(8, 8, 4), b512, 0, stream>>>(
      ATTNO, WTO, PARTSW, nullptr, nullptr, nullptr, TT, 2048, 2048, 512);
  // P4: fused residual+rmsnorm+router (tail blocks transpose wsd); scan; assign
  zero_k<<<24, b256, 0, stream>>>(STOK, SW);
  fuserouter_k<<<TT + 344, b256, 0, stream>>>(x, PARTSW, fnw, rw, X2, HN, TOPI, TOPW, PROBS,
                                              wsd, WTSd);
  scan2_k<<<1, b256, 0, stream>>>(TOPI, PROBS, CURS, TILT, AUXO);
  assign_k<<<8, b256, 0, stream>>>(TOPI, TOPW, CURS, STOK, SW, TSLOT);
  // P5/P6 front: transpose all gate/up weights, then MERGED shared+expert gate+up
  transp_k<<<dim3(172, 32, 1), b256, 0, stream>>>(wsg, WTSg, 2048, FSH);
  transp_k<<<dim3(172, 32, 1), b256, 0, stream>>>(wsu, WTSu, 2048, FSH);
  transp_k<<<dim3(32, 32, 8), b256, 0, stream>>>(wg, WTEg, 2048, 2048);
  transp_k<<<dim3(32, 32, 8), b256, 0, stream>>>(wu, WTEu, 2048, 2048);
  gemm_gu_m<<<dim3(86, 32, 1), b512, 0, stream>>>(
      HN, WTSg, WTSu, G, WTEg, WTEu, ACT, STOK, TILT, 2048);
  // shared down (split-K x4) + reduce into out
  gemm8<10, true, false><<<dim3(8, 8, 4), b512, 0, stream>>>(
      G, WTSd, PARTSD, nullptr, nullptr, nullptr, TT, 2048, FSH, 2816);
  redbf_k<<<2048, b256, 0, stream>>>(out, X2, PARTSD);
  // expert down
  gemm8<4, false, true><<<dim3(8, 24, 1), b512, 0, stream>>>(
      ACT, WTEd, ROUTED, nullptr, SW, TILT, 0, 2048, 2048, 0);
  // P7: out += routed
  final_k<<<TT, b256, 0, stream>>>(out, ROUTED, TSLOT);
}

// Round 13
// 835.029 us; speedup vs baseline: 1.0421x; 1.0130x over previous
//
#include <hip/hip_runtime.h>

typedef unsigned short u16;
typedef unsigned int u32;
typedef unsigned long long u64;
typedef __attribute__((ext_vector_type(4))) unsigned short u16x4;
typedef __attribute__((ext_vector_type(8))) unsigned short u16x8;
typedef __attribute__((ext_vector_type(4))) float f32x4;
typedef __attribute__((ext_vector_type(8))) __bf16 bf16x8;

#define DD 2048
#define TT 2048
#define FSH 11008

__device__ __forceinline__ float bf2f(u16 u) {
  union { u32 i; float f; } v; v.i = ((u32)u) << 16; return v.f;
}
__device__ __forceinline__ u16 f2bf(float f) {
  union { float f; u32 i; } v; v.f = f;
  u32 r = v.i + 0x7fffu + ((v.i >> 16) & 1u);
  return (u16)(r >> 16);
}
__device__ __forceinline__ void gld16(const void* g, void* l) {
  __builtin_amdgcn_global_load_lds((const __attribute__((address_space(1))) void*)g,
                                   (__attribute__((address_space(3))) void*)l, 16, 0, 0);
}

#define MFMA16(d, a, b) d = __builtin_amdgcn_mfma_f32_16x16x32_bf16(a, b, d, 0, 0, 0)

// ---------------- 64x64 tile transpose helper (256 threads, XOR-swizzled LDS) ----------
__device__ __forceinline__ void ttile(const float* __restrict__ Wm, u16* __restrict__ Wtm,
                                      int R, int C, int n0, int k0, u16* tile, int t) {
#pragma unroll
  for (int p = 0; p < 4; ++p) {
    const int kk = (t >> 4) + p * 16;
    const int nn = (t & 15) * 4;
    float4 v = *(const float4*)(Wm + (size_t)(k0 + kk) * C + n0 + nn);
    const float vv[4] = {v.x, v.y, v.z, v.w};
#pragma unroll
    for (int j = 0; j < 4; ++j) {
      const int n = nn + j;
      tile[n * 80 + (kk ^ (((n >> 2) & 7) << 3))] = f2bf(vv[j]);
    }
  }
  __syncthreads();
#pragma unroll
  for (int p = 0; p < 2; ++p) {
    const int n = (t >> 3) + p * 32;
    const int c = t & 7;
    u16x8 v = *(const u16x8*)(tile + n * 80 + ((c * 8) ^ (((n >> 2) & 7) << 3)));
    *(u16x8*)(Wtm + (size_t)(n0 + n) * R + k0 + c * 8) = v;
  }
}

// ---------------- RMSNorm: f32 row -> bf16 row ----------------
__global__ __launch_bounds__(256) void rmsnorm_k(const float* __restrict__ x,
                                                 const float* __restrict__ w,
                                                 u16* __restrict__ out) {
  const int t = threadIdx.x;
  const float* xr = x + (size_t)blockIdx.x * DD;
  float4 a = *(const float4*)(xr + t * 8);
  float4 b = *(const float4*)(xr + t * 8 + 4);
  float ss = a.x*a.x + a.y*a.y + a.z*a.z + a.w*a.w
           + b.x*b.x + b.y*b.y + b.z*b.z + b.w*b.w;
#pragma unroll
  for (int m = 1; m < 64; m <<= 1) ss += __shfl_xor(ss, m);
  __shared__ float red[4];
  if ((t & 63) == 0) red[t >> 6] = ss;
  __syncthreads();
  float sc = rsqrtf((red[0] + red[1] + red[2] + red[3]) * (1.f / DD) + 1e-6f);
  float4 wa = *(const float4*)(w + t * 8);
  float4 wb = *(const float4*)(w + t * 8 + 4);
  u16x8 o;
  o[0] = f2bf(a.x * sc * wa.x); o[1] = f2bf(a.y * sc * wa.y);
  o[2] = f2bf(a.z * sc * wa.z); o[3] = f2bf(a.w * sc * wa.w);
  o[4] = f2bf(b.x * sc * wb.x); o[5] = f2bf(b.y * sc * wb.y);
  o[6] = f2bf(b.z * sc * wb.z); o[7] = f2bf(b.w * sc * wb.w);
  *(u16x8*)(out + (size_t)blockIdx.x * DD + t * 8) = o;
}

// ---------------- Standalone transpose+convert: W[R][C] f32 -> Wt[C][R] bf16 ----------
__global__ __launch_bounds__(256) void transp_k(const float* __restrict__ W,
                                                u16* __restrict__ Wt, int R, int C) {
  __shared__ u16 tile[64 * 80];
  const size_t msz = (size_t)R * C;
  ttile(W + msz * blockIdx.z, Wt + msz * blockIdx.z, R, C,
        blockIdx.x * 64, blockIdx.y * 64, tile, threadIdx.x);
}

// ---------------- GEMM8: 256^2, 8-wave, 8-phase ----------------
// EPI: 2=bf16, 3=bf16 silu(aux)*acc, 4=bf16 slotw[row]*acc, 10=bf16 parts, 11=f32 parts
template <int EPI, bool SPLITK, bool EXPERT>
__global__ __launch_bounds__(512, 2) void gemm8(
    const u16* __restrict__ A, const u16* __restrict__ Bt, void* __restrict__ Cp,
    const u16* __restrict__ aux, const float* __restrict__ slotw,
    const int* __restrict__ tiletab, int M, int N, int K, int Kc) {
  __shared__ char lds[131072];
  const int t = threadIdx.x, w = t >> 6, l = t & 63;
  int m0, n0;
  if constexpr (EXPERT) {
    const int ntil = tiletab[0];
    if ((int)blockIdx.y >= ntil) return;
    const int e = tiletab[1 + blockIdx.y * 2];
    m0 = tiletab[2 + blockIdx.y * 2];
    n0 = blockIdx.x * 256;
    Bt += (size_t)e * N * K;
  } else {
    const int gx = gridDim.x, gy = gridDim.y;
    const int nwg = gx * gy;          // % 8 == 0
    int wg = blockIdx.y * gx + blockIdx.x;
    wg = (wg & 7) * (nwg >> 3) + (wg >> 3);   // XCD swizzle (bijective)
    m0 = (wg % gy) * 256;             // n-major
    n0 = (wg / gy) * 256;
  }
  int kbase = 0, KC = K;
  if constexpr (SPLITK) {
    kbase = blockIdx.z * Kc;
    const int rem = K - kbase;
    KC = rem < Kc ? rem : Kc;
  }
  const int ktiles = KC >> 6;
  const int wm = w >> 2, wn = w & 3;
  const int l15 = l & 15, l4 = l >> 4;
  const int sro = l >> 3, sc = l & 7;

  const u16* sgp[2][2][2];
  u32 sdo[2][2][2];
#pragma unroll
  for (int isB = 0; isB < 2; ++isB)
#pragma unroll
    for (int h = 0; h < 2; ++h)
#pragma unroll
      for (int i = 0; i < 2; ++i) {
        const int q = i * 8 + w;
        const int r0 = isB ? (((q >> 2) << 6) + h * 32 + (q & 3) * 8)
                           : (((q & 8) << 4) + h * 64 + (q & 7) * 8);
        const int r = r0 + sro;
        const int cl = sc ^ (r & 7);
        const u16* base = isB ? (Bt + (size_t)(n0 + r) * K) : (A + (size_t)(m0 + r) * K);
        sgp[isB][h][i] = base + kbase + cl * 8;
        sdo[isB][h][i] = (u32)(isB * 32768 + r0 * 128);
      }
  auto stage = [&](int b, int isB, int h, int kt) {
    const int kk = kt < ktiles ? kt : ktiles - 1;
#pragma unroll
    for (int i = 0; i < 2; ++i)
      gld16(sgp[isB][h][i] + kk * 64, lds + b * 65536 + sdo[isB][h][i]);
  };
  auto ldA = [&](int b, int mi, int ks) {
    const int row = wm * 128 + mi * 16 + l15;
    const int ch = (ks * 4 + l4) ^ (row & 7);
    return *(const bf16x8*)(lds + b * 65536 + row * 128 + ch * 16);
  };
  auto ldB = [&](int b, int ni, int ks) {
    const int row = wn * 64 + ni * 16 + l15;
    const int ch = (ks * 4 + l4) ^ (row & 7);
    return *(const bf16x8*)(lds + b * 65536 + 32768 + row * 128 + ch * 16);
  };

  f32x4 acc[8][4] = {};
  bf16x8 aR[4][2], b0[2][2], b1[2][2];

  stage(0, 0, 0, 0); stage(0, 1, 0, 0); stage(0, 1, 1, 0); stage(0, 0, 1, 0);
  stage(1, 0, 0, 1); stage(1, 1, 1, 1); stage(1, 0, 1, 1);
  asm volatile("s_waitcnt vmcnt(6)" ::: "memory");
  __builtin_amdgcn_s_barrier();

  for (int kt = 0; kt < ktiles; kt += 2) {
#pragma unroll
    for (int mi = 0; mi < 4; ++mi) { aR[mi][0] = ldA(0, mi, 0); aR[mi][1] = ldA(0, mi, 1); }
#pragma unroll
    for (int ni = 0; ni < 2; ++ni) { b0[ni][0] = ldB(0, ni, 0); b0[ni][1] = ldB(0, ni, 1); }
    stage(1, 1, 0, kt + 1);
    __builtin_amdgcn_s_barrier();
    asm volatile("s_waitcnt lgkmcnt(0)" ::: "memory");
    __builtin_amdgcn_s_setprio(1);
#pragma unroll
    for (int mi = 0; mi < 4; ++mi)
#pragma unroll
      for (int ni = 0; ni < 2; ++ni) {
        MFMA16(acc[mi][ni], aR[mi][0], b0[ni][0]);
        MFMA16(acc[mi][ni], aR[mi][1], b0[ni][1]);
      }
    __builtin_amdgcn_s_setprio(0);
    __builtin_amdgcn_s_barrier();
#pragma unroll
    for (int ni = 0; ni < 2; ++ni) { b1[ni][0] = ldB(0, ni + 2, 0); b1[ni][1] = ldB(0, ni + 2, 1); }
    stage(0, 0, 0, kt + 2);
    __builtin_amdgcn_s_barrier();
    asm volatile("s_waitcnt lgkmcnt(0)" ::: "memory");
    __builtin_amdgcn_s_setprio(1);
#pragma unroll
    for (int mi = 0; mi < 4; ++mi)
#pragma unroll
      for (int ni = 0; ni < 2; ++ni) {
        MFMA16(acc[mi][ni + 2], aR[mi][0], b1[ni][0]);
        MFMA16(acc[mi][ni + 2], aR[mi][1], b1[ni][1]);
      }
    __builtin_amdgcn_s_setprio(0);
    __builtin_amdgcn_s_barrier();
#pragma unroll
    for (int mi = 0; mi < 4; ++mi) { aR[mi][0] = ldA(0, mi + 4, 0); aR[mi][1] = ldA(0, mi + 4, 1); }
    stage(0, 1, 1, kt + 2);
    __builtin_amdgcn_s_barrier();
    asm volatile("s_waitcnt lgkmcnt(0)" ::: "memory");
    __builtin_amdgcn_s_setprio(1);
#pragma unroll
    for (int mi = 0; mi < 4; ++mi)
#pragma unroll
      for (int ni = 0; ni < 2; ++ni) {
        MFMA16(acc[mi + 4][ni + 2], aR[mi][0], b1[ni][0]);
        MFMA16(acc[mi + 4][ni + 2], aR[mi][1], b1[ni][1]);
      }
    __builtin_amdgcn_s_setprio(0);
    __builtin_amdgcn_s_barrier();
    stage(0, 0, 1, kt + 2);
    __builtin_amdgcn_s_barrier();
    __builtin_amdgcn_s_setprio(1);
#pragma unroll
    for (int mi = 0; mi < 4; ++mi)
#pragma unroll
      for (int ni = 0; ni < 2; ++ni) {
        MFMA16(acc[mi + 4][ni], aR[mi][0], b0[ni][0]);
        MFMA16(acc[mi + 4][ni], aR[mi][1], b0[ni][1]);
      }
    __builtin_amdgcn_s_setprio(0);
    asm volatile("s_waitcnt vmcnt(6)" ::: "memory");
    __builtin_amdgcn_s_barrier();
#pragma unroll
    for (int mi = 0; mi < 4; ++mi) { aR[mi][0] = ldA(1, mi, 0); aR[mi][1] = ldA(1, mi, 1); }
#pragma unroll
    for (int ni = 0; ni < 2; ++ni) { b0[ni][0] = ldB(1, ni, 0); b0[ni][1] = ldB(1, ni, 1); }
    stage(0, 1, 0, kt + 2);
    __builtin_amdgcn_s_barrier();
    asm volatile("s_waitcnt lgkmcnt(0)" ::: "memory");
    __builtin_amdgcn_s_setprio(1);
#pragma unroll
    for (int mi = 0; mi < 4; ++mi)
#pragma unroll
      for (int ni = 0; ni < 2; ++ni) {
        MFMA16(acc[mi][ni], aR[mi][0], b0[ni][0]);
        MFMA16(acc[mi][ni], aR[mi][1], b0[ni][1]);
      }
    __builtin_amdgcn_s_setprio(0);
    __builtin_amdgcn_s_barrier();
#pragma unroll
    for (int ni = 0; ni < 2; ++ni) { b1[ni][0] = ldB(1, ni + 2, 0); b1[ni][1] = ldB(1, ni + 2, 1); }
    stage(1, 0, 0, kt + 3);
    __builtin_amdgcn_s_barrier();
    asm volatile("s_waitcnt lgkmcnt(0)" ::: "memory");
    __builtin_amdgcn_s_setprio(1);
#pragma unroll
    for (int mi = 0; mi < 4; ++mi)
#pragma unroll
      for (int ni = 0; ni < 2; ++ni) {
        MFMA16(acc[mi][ni + 2], aR[mi][0], b1[ni][0]);
        MFMA16(acc[mi][ni + 2], aR[mi][1], b1[ni][1]);
      }
    __builtin_amdgcn_s_setprio(0);
    __builtin_amdgcn_s_barrier();
#pragma unroll
    for (int mi = 0; mi < 4; ++mi) { aR[mi][0] = ldA(1, mi + 4, 0); aR[mi][1] = ldA(1, mi + 4, 1); }
    stage(1, 1, 1, kt + 3);
    __builtin_amdgcn_s_barrier();
    asm volatile("s_waitcnt lgkmcnt(0)" ::: "memory");
    __builtin_amdgcn_s_setprio(1);
#pragma unroll
    for (int mi = 0; mi < 4; ++mi)
#pragma unroll
      for (int ni = 0; ni < 2; ++ni) {
        MFMA16(acc[mi + 4][ni + 2], aR[mi][0], b1[ni][0]);
        MFMA16(acc[mi + 4][ni + 2], aR[mi][1], b1[ni][1]);
      }
    __builtin_amdgcn_s_setprio(0);
    __builtin_amdgcn_s_barrier();
    stage(1, 0, 1, kt + 3);
    __builtin_amdgcn_s_barrier();
    __builtin_amdgcn_s_setprio(1);
#pragma unroll
    for (int mi = 0; mi < 4; ++mi)
#pragma unroll
      for (int ni = 0; ni < 2; ++ni) {
        MFMA16(acc[mi + 4][ni], aR[mi][0], b0[ni][0]);
        MFMA16(acc[mi + 4][ni], aR[mi][1], b0[ni][1]);
      }
    __builtin_amdgcn_s_setprio(0);
    asm volatile("s_waitcnt vmcnt(6)" ::: "memory");
    __builtin_amdgcn_s_barrier();
  }

  u16* C16 = (u16*)Cp;
  float* Cf = (float*)Cp;
  if constexpr (EPI == 10) C16 += (size_t)blockIdx.z * ((size_t)M * N);
  if constexpr (EPI == 11) Cf += (size_t)blockIdx.z * ((size_t)M * N);
#pragma unroll
  for (int mi = 0; mi < 8; ++mi)
#pragma unroll
    for (int rr = 0; rr < 4; ++rr) {
      const int row = m0 + wm * 128 + mi * 16 + l4 * 4 + rr;
#pragma unroll
      for (int ni = 0; ni < 4; ++ni) {
        const int col = n0 + wn * 64 + ni * 16 + l15;
        const size_t idx = (size_t)row * N + col;
        const float v = acc[mi][ni][rr];
        if constexpr (EPI == 11) {
          Cf[idx] = v;
        } else if constexpr (EPI == 3) {
          const float g = bf2f(aux[idx]);
          C16[idx] = f2bf(v * g / (1.f + __expf(-g)));
        } else if constexpr (EPI == 4) {
          C16[idx] = f2bf(slotw[row] * v);
        } else {
          C16[idx] = f2bf(v);
        }
      }
    }
}

// ---------------- GEMM_GU: fused gate+up, 256m x 128n-per-matrix, 8-phase ----------------
template <bool EXPERT>
__global__ __launch_bounds__(512, 2) void gemm_gu(
    const u16* __restrict__ A, const u16* __restrict__ Btg, const u16* __restrict__ Btu,
    u16* __restrict__ act, const int* __restrict__ slot_tok, const int* __restrict__ tiletab,
    int K, int LDC) {
  __shared__ char lds[131072];
  const int t = threadIdx.x, w = t >> 6, l = t & 63;
  int m0, nt;
  const u16 *Bg, *Bu;
  if constexpr (EXPERT) {
    const int ntil = tiletab[0];
    if ((int)blockIdx.y >= ntil) return;
    const int e = tiletab[1 + blockIdx.y * 2];
    m0 = tiletab[2 + blockIdx.y * 2];
    nt = blockIdx.x;
    const size_t boff = (size_t)e * LDC * K;
    Bg = Btg + boff;
    Bu = Btu + boff;
  } else {
    const int gx = gridDim.x;
    const int nwg = gx * 8;
    int wg = blockIdx.y * gx + blockIdx.x;
    wg = (wg & 7) * (nwg >> 3) + (wg >> 3);
    m0 = (wg & 7) * 256;
    nt = wg >> 3;
    Bg = Btg;
    Bu = Btu;
  }
  const int ktiles = K >> 6;
  const int wm = w >> 2, wn = w & 3;
  const int l15 = l & 15, l4 = l >> 4;
  const int sro = l >> 3, sc = l & 7;

  const u16* sga[2][2]; u32 sda[2][2];
#pragma unroll
  for (int h = 0; h < 2; ++h)
#pragma unroll
    for (int i = 0; i < 2; ++i) {
      const int q = i * 8 + w;
      const int r0 = ((q & 8) << 4) + h * 64 + (q & 7) * 8;
      const int r = r0 + sro;
      const int cl = sc ^ (r & 7);
      size_t arow;
      if constexpr (EXPERT) arow = (size_t)slot_tok[m0 + r];
      else arow = (size_t)(m0 + r);
      sga[h][i] = A + arow * K + cl * 8;
      sda[h][i] = (u32)(r0 * 128);
    }
  const u16* sgb[2][2]; u32 sdb[2][2];
#pragma unroll
  for (int mat = 0; mat < 2; ++mat)
#pragma unroll
    for (int i = 0; i < 2; ++i) {
      const int q = i * 8 + w;
      const int r0 = q * 8;
      const int r = r0 + sro;
      const int cl = sc ^ (r & 7);
      const u16* B = mat ? Bu : Bg;
      sgb[mat][i] = B + (size_t)(nt * 128 + r) * K + cl * 8;
      sdb[mat][i] = (u32)(32768 + mat * 16384 + r0 * 128);
    }
  auto stgA = [&](int b, int h, int kt) {
    const int kk = kt < ktiles ? kt : ktiles - 1;
#pragma unroll
    for (int i = 0; i < 2; ++i) gld16(sga[h][i] + kk * 64, lds + b * 65536 + sda[h][i]);
  };
  auto stgB = [&](int b, int mat, int kt) {
    const int kk = kt < ktiles ? kt : ktiles - 1;
#pragma unroll
    for (int i = 0; i < 2; ++i) gld16(sgb[mat][i] + kk * 64, lds + b * 65536 + sdb[mat][i]);
  };
  auto ldA = [&](int b, int mi, int ks) {
    const int row = wm * 128 + mi * 16 + l15;
    const int ch = (ks * 4 + l4) ^ (row & 7);
    return *(const bf16x8*)(lds + b * 65536 + row * 128 + ch * 16);
  };
  auto ldB = [&](int b, int mat, int ni, int ks) {
    const int row = wn * 32 + ni * 16 + l15;
    const int ch = (ks * 4 + l4) ^ (row & 7);
    return *(const bf16x8*)(lds + b * 65536 + 32768 + mat * 16384 + row * 128 + ch * 16);
  };

  f32x4 accg[8][2] = {}, accu[8][2] = {};
  bf16x8 aR[4][2], bg[2][2], bu[2][2];

  stgA(0, 0, 0); stgB(0, 0, 0); stgB(0, 1, 0); stgA(0, 1, 0);
  stgA(1, 0, 1); stgB(1, 1, 1); stgA(1, 1, 1);
  asm volatile("s_waitcnt vmcnt(6)" ::: "memory");
  __builtin_amdgcn_s_barrier();

  for (int kt = 0; kt < ktiles; kt += 2) {
#pragma unroll
    for (int mi = 0; mi < 4; ++mi) { aR[mi][0] = ldA(0, mi, 0); aR[mi][1] = ldA(0, mi, 1); }
#pragma unroll
    for (int ni = 0; ni < 2; ++ni) { bg[ni][0] = ldB(0, 0, ni, 0); bg[ni][1] = ldB(0, 0, ni, 1); }
    stgB(1, 0, kt + 1);
    __builtin_amdgcn_s_barrier();
    asm volatile("s_waitcnt lgkmcnt(0)" ::: "memory");
    __builtin_amdgcn_s_setprio(1);
#pragma unroll
    for (int mi = 0; mi < 4; ++mi)
#pragma unroll
      for (int ni = 0; ni < 2; ++ni) {
        MFMA16(accg[mi][ni], aR[mi][0], bg[ni][0]);
        MFMA16(accg[mi][ni], aR[mi][1], bg[ni][1]);
      }
    __builtin_amdgcn_s_setprio(0);
    __builtin_amdgcn_s_barrier();
#pragma unroll
    for (int ni = 0; ni < 2; ++ni) { bu[ni][0] = ldB(0, 1, ni, 0); bu[ni][1] = ldB(0, 1, ni, 1); }
    stgA(0, 0, kt + 2);
    __builtin_amdgcn_s_barrier();
    asm volatile("s_waitcnt lgkmcnt(0)" ::: "memory");
    __builtin_amdgcn_s_setprio(1);
#pragma unroll
    for (int mi = 0; mi < 4; ++mi)
#pragma unroll
      for (int ni = 0; ni < 2; ++ni) {
        MFMA16(accu[mi][ni], aR[mi][0], bu[ni][0]);
        MFMA16(accu[mi][ni], aR[mi][1], bu[ni][1]);
      }
    __builtin_amdgcn_s_setprio(0);
    __builtin_amdgcn_s_barrier();
#pragma unroll
    for (int mi = 0; mi < 4; ++mi) { aR[mi][0] = ldA(0, mi + 4, 0); aR[mi][1] = ldA(0, mi + 4, 1); }
    stgB(0, 1, kt + 2);
    __builtin_amdgcn_s_barrier();
    asm volatile("s_waitcnt lgkmcnt(0)" ::: "memory");
    __builtin_amdgcn_s_setprio(1);
#pragma unroll
    for (int mi = 0; mi < 4; ++mi)
#pragma unroll
      for (int ni = 0; ni < 2; ++ni) {
        MFMA16(accu[mi + 4][ni], aR[mi][0], bu[ni][0]);
        MFMA16(accu[mi + 4][ni], aR[mi][1], bu[ni][1]);
      }
    __builtin_amdgcn_s_setprio(0);
    __builtin_amdgcn_s_barrier();
    stgA(0, 1, kt + 2);
    __builtin_amdgcn_s_barrier();
    __builtin_amdgcn_s_setprio(1);
#pragma unroll
    for (int mi = 0; mi < 4; ++mi)
#pragma unroll
      for (int ni = 0; ni < 2; ++ni) {
        MFMA16(accg[mi + 4][ni], aR[mi][0], bg[ni][0]);
        MFMA16(accg[mi + 4][ni], aR[mi][1], bg[ni][1]);
      }
    __builtin_amdgcn_s_setprio(0);
    asm volatile("s_waitcnt vmcnt(6)" ::: "memory");
    __builtin_amdgcn_s_barrier();
#pragma unroll
    for (int mi = 0; mi < 4; ++mi) { aR[mi][0] = ldA(1, mi, 0); aR[mi][1] = ldA(1, mi, 1); }
#pragma unroll
    for (int ni = 0; ni < 2; ++ni) { bg[ni][0] = ldB(1, 0, ni, 0); bg[ni][1] = ldB(1, 0, ni, 1); }
    stgB(0, 0, kt + 2);
    __builtin_amdgcn_s_barrier();
    asm volatile("s_waitcnt lgkmcnt(0)" ::: "memory");
    __builtin_amdgcn_s_setprio(1);
#pragma unroll
    for (int mi = 0; mi < 4; ++mi)
#pragma unroll
      for (int ni = 0; ni < 2; ++ni) {
        MFMA16(accg[mi][ni], aR[mi][0], bg[ni][0]);
        MFMA16(accg[mi][ni], aR[mi][1], bg[ni][1]);
      }
    __builtin_amdgcn_s_setprio(0);
    __builtin_amdgcn_s_barrier();
#pragma unroll
    for (int ni = 0; ni < 2; ++ni) { bu[ni][0] = ldB(1, 1, ni, 0); bu[ni][1] = ldB(1, 1, ni, 1); }
    stgA(1, 0, kt + 3);
    __builtin_amdgcn_s_barrier();
    asm volatile("s_waitcnt lgkmcnt(0)" ::: "memory");
    __builtin_amdgcn_s_setprio(1);
#pragma unroll
    for (int mi = 0; mi < 4; ++mi)
#pragma unroll
      for (int ni = 0; ni < 2; ++ni) {
        MFMA16(accu[mi][ni], aR[mi][0], bu[ni][0]);
        MFMA16(accu[mi][ni], aR[mi][1], bu[ni][1]);
      }
    __builtin_amdgcn_s_setprio(0);
    __builtin_amdgcn_s_barrier();
#pragma unroll
    for (int mi = 0; mi < 4; ++mi) { aR[mi][0] = ldA(1, mi + 4, 0); aR[mi][1] = ldA(1, mi + 4, 1); }
    stgB(1, 1, kt + 3);
    __builtin_amdgcn_s_barrier();
    asm volatile("s_waitcnt lgkmcnt(0)" ::: "memory");
    __builtin_amdgcn_s_setprio(1);
#pragma unroll
    for (int mi = 0; mi < 4; ++mi)
#pragma unroll
      for (int ni = 0; ni < 2; ++ni) {
        MFMA16(accu[mi + 4][ni], aR[mi][0], bu[ni][0]);
        MFMA16(accu[mi + 4][ni], aR[mi][1], bu[ni][1]);
      }
    __builtin_amdgcn_s_setprio(0);
    __builtin_amdgcn_s_barrier();
    stgA(1, 1, kt + 3);
    __builtin_amdgcn_s_barrier();
    __builtin_amdgcn_s_setprio(1);
#pragma unroll
    for (int mi = 0; mi < 4; ++mi)
#pragma unroll
      for (int ni = 0; ni < 2; ++ni) {
        MFMA16(accg[mi + 4][ni], aR[mi][0], bg[ni][0]);
        MFMA16(accg[mi + 4][ni], aR[mi][1], bg[ni][1]);
      }
    __builtin_amdgcn_s_setprio(0);
    asm volatile("s_waitcnt vmcnt(6)" ::: "memory");
    __builtin_amdgcn_s_barrier();
  }

#pragma unroll
  for (int mi = 0; mi < 8; ++mi)
#pragma unroll
    for (int rr = 0; rr < 4; ++rr) {
      const int row = m0 + wm * 128 + mi * 16 + l4 * 4 + rr;
#pragma unroll
      for (int ni = 0; ni < 2; ++ni) {
        const int col = nt * 128 + wn * 32 + ni * 16 + l15;
        const float g = accg[mi][ni][rr];
        const float u = accu[mi][ni][rr];
        act[(size_t)row * LDC + col] = f2bf(u * g / (1.f + __expf(-g)));
      }
    }
}

// ---------------- split-K reduce (bf16 parts x4): dst = base + sum ----------------
__global__ __launch_bounds__(256) void redbf_k(float* __restrict__ dst,
                                               const float* __restrict__ base,
                                               const u16* __restrict__ parts) {
  const int i = blockIdx.x * 256 + threadIdx.x;
  float s[8];
  const float* bp = base + (size_t)i * 8;
#pragma unroll
  for (int j = 0; j < 8; ++j) s[j] = bp[j];
#pragma unroll
  for (int p = 0; p < 4; ++p) {
    u16x8 v = ((const u16x8*)parts)[(size_t)p * 524288 + i];
#pragma unroll
    for (int j = 0; j < 8; ++j) s[j] += bf2f(v[j]);
  }
  float* dp = dst + (size_t)i * 8;
#pragma unroll
  for (int j = 0; j < 8; ++j) dp[j] = s[j];
}

// ---------------- RoPE from bf16 split-K parts + pack Q/K/V + emit new_k/new_v ----------
__global__ __launch_bounds__(256) void rope_k(
    const u16* __restrict__ p0, const u16* __restrict__ p1,
    const float* __restrict__ cosb, const float* __restrict__ sinb,
    const float* __restrict__ bq, const float* __restrict__ bk, const float* __restrict__ bv,
    u16* __restrict__ QR, u16* __restrict__ KR, u16* __restrict__ VB,
    float* __restrict__ NK, float* __restrict__ NV) {
  const int s = blockIdx.x, b = blockIdx.y, t = threadIdx.x;
  const size_t tok = (size_t)b * 1024 + s;
  const u16* r0 = p0 + tok * 3072;
  const u16* r1 = p1 + tok * 3072;
  const float* cr = cosb + s * 128;
  const float* sr = sinb + s * 128;
  for (int i = t; i < 1024; i += 256) {
    const int h = i >> 6, d = i & 63;
    const float v1 = bf2f(r0[h * 128 + d]) + bf2f(r1[h * 128 + d]) + bq[h * 128 + d];
    const float v2 = bf2f(r0[h * 128 + d + 64]) + bf2f(r1[h * 128 + d + 64]) + bq[h * 128 + d + 64];
    const float o1 = v1 * cr[d] - v2 * sr[d];
    const float o2 = v2 * cr[d + 64] + v1 * sr[d + 64];
    const size_t qb = (((size_t)(b * 16 + h)) * 1024 + s) * 128;
    QR[qb + d] = f2bf(o1);
    QR[qb + d + 64] = f2bf(o2);
  }
  {
    const int h = t >> 6, d = t & 63;
    const float v1 = bf2f(r0[2048 + h * 128 + d]) + bf2f(r1[2048 + h * 128 + d]) + bk[h * 128 + d];
    const float v2 = bf2f(r0[2048 + h * 128 + d + 64]) + bf2f(r1[2048 + h * 128 + d + 64]) + bk[h * 128 + d + 64];
    const float o1 = v1 * cr[d] - v2 * sr[d];
    const float o2 = v2 * cr[d + 64] + v1 * sr[d + 64];
    const size_t kb = (((size_t)(b * 4 + h)) * 1024 + s) * 128;
    KR[kb + d] = f2bf(o1);
    KR[kb + d + 64] = f2bf(o2);
    const size_t ob = tok * 2048;
#pragma unroll
    for (int rep = 0; rep < 4; ++rep) {
      NK[ob + (h * 4 + rep) * 128 + d] = o1;
      NK[ob + (h * 4 + rep) * 128 + d + 64] = o2;
    }
  }
  for (int i = t; i < 512; i += 256) {
    const int h = i >> 7, d = i & 127;
    const float v = bf2f(r0[2560 + i]) + bf2f(r1[2560 + i]) + bv[i];
    VB[(((size_t)(b * 4 + h)) * 1024 + s) * 128 + d] = f2bf(v);
    const size_t ob = tok * 2048;
#pragma unroll
    for (int rep = 0; rep < 4; ++rep) NV[ob + (h * 4 + rep) * 128 + d] = v;
  }
}

// ---------------- Flash attention + fused wd transpose (z==2 plane) ----------------
__global__ __launch_bounds__(256) void attn_k(const u16* __restrict__ Q,
                                              const u16* __restrict__ Kc,
                                              const u16* __restrict__ Vc,
                                              u16* __restrict__ O,
                                              const float* __restrict__ wdsrc,
                                              u16* __restrict__ wtd) {
  __shared__ u16 Ks[64 * 128];
  __shared__ u16 Vt[128 * 66];
  __shared__ u16 Ps[4][16 * 68];
  const int t = threadIdx.x, w = t >> 6, l = t & 63;
  if (blockIdx.z == 2) {
    u16* tile = Ks;  // 64*80 <= 64*128
    const int bi = blockIdx.y * 16 + blockIdx.x;
#pragma unroll 1
    for (int i = 0; i < 32; ++i) {
      const int ti = bi * 32 + i;
      const int e = ti >> 10, rem = ti & 1023;
      ttile(wdsrc + (size_t)e * 4194304, wtd + (size_t)e * 4194304,
            2048, 2048, (rem & 31) * 64, (rem >> 5) * 64, tile, t);
      __syncthreads();
    }
    return;
  }
  const int qt = blockIdx.x, h = blockIdx.y, b = blockIdx.z;
  const int kvh = h >> 2;
  const int l15 = l & 15, l4 = l >> 4;
  bf16x8 qf[4];
  {
    const u16* qb = Q + (((size_t)(b * 16 + h)) * 1024 + qt * 64 + w * 16 + l15) * 128 + l4 * 8;
#pragma unroll
    for (int c = 0; c < 4; ++c) qf[c] = *(const bf16x8*)(qb + c * 32);
  }
  float m_run[4] = {-1e30f, -1e30f, -1e30f, -1e30f};
  float l_run[4] = {0.f, 0.f, 0.f, 0.f};
  f32x4 accO[8] = {};
  const size_t kvbase = ((size_t)(b * 4 + kvh)) * 1024 * 128;
  const int ntiles = qt + 1;
  for (int kt = 0; kt < ntiles; ++kt) {
    __syncthreads();
    {
      const int key = t >> 2;
      const u16* kg = Kc + kvbase + (size_t)(kt * 64 + key) * 128;
      const u16* vg = Vc + kvbase + (size_t)(kt * 64 + key) * 128;
      const int sw = (key & 7) << 4;
#pragma unroll
      for (int p = 0; p < 4; ++p) {
        const int ch = (t & 3) * 4 + p;
        *(u16x8*)((char*)Ks + key * 256 + ((ch * 16) ^ sw)) = *(const u16x8*)(kg + ch * 8);
        const int d0 = ch * 8;
        u16x8 vv = *(const u16x8*)(vg + d0);
#pragma unroll
        for (int j = 0; j < 8; ++j) Vt[(d0 + j) * 66 + key] = vv[j];
      }
    }
    __syncthreads();
    f32x4 sf[4] = {};
    __builtin_amdgcn_s_setprio(1);
#pragma unroll
    for (int nf = 0; nf < 4; ++nf) {
      const int keyl = nf * 16 + l15;
      const int sw = (keyl & 7) << 4;
      const char* kbase = (const char*)Ks + keyl * 256;
#pragma unroll
      for (int c = 0; c < 4; ++c) {
        bf16x8 kf = *(const bf16x8*)(kbase + ((c * 64 + l4 * 16) ^ sw));
        sf[nf] = __builtin_amdgcn_mfma_f32_16x16x32_bf16(qf[c], kf, sf[nf], 0, 0, 0);
      }
    }
    __builtin_amdgcn_s_setprio(0);
    const int qg0 = qt * 64 + w * 16 + l4 * 4;
    float alpha[4];
#pragma unroll
    for (int r = 0; r < 4; ++r) {
      const int qg = qg0 + r;
      float tm = -1e30f;
#pragma unroll
      for (int nf = 0; nf < 4; ++nf) {
        const int kg = kt * 64 + nf * 16 + l15;
        float sv = sf[nf][r] * 0.088388347648318447f;
        sv = (kg <= qg) ? sv : -1e30f;
        sf[nf][r] = sv;
        tm = fmaxf(tm, sv);
      }
#pragma unroll
      for (int mm = 1; mm < 16; mm <<= 1) tm = fmaxf(tm, __shfl_xor(tm, mm));
      const float mn = fmaxf(m_run[r], tm);
      alpha[r] = __expf(m_run[r] - mn);
      m_run[r] = mn;
      float rs = 0.f;
#pragma unroll
      for (int nf = 0; nf < 4; ++nf) {
        const float p = __expf(sf[nf][r] - mn);
        sf[nf][r] = p;
        rs += p;
      }
#pragma unroll
      for (int mm = 1; mm < 16; mm <<= 1) rs += __shfl_xor(rs, mm);
      l_run[r] = l_run[r] * alpha[r] + rs;
    }
#pragma unroll
    for (int nf = 0; nf < 8; ++nf)
#pragma unroll
      for (int r = 0; r < 4; ++r) accO[nf][r] *= alpha[r];
#pragma unroll
    for (int nf = 0; nf < 4; ++nf)
#pragma unroll
      for (int r = 0; r < 4; ++r)
        Ps[w][(l4 * 4 + r) * 68 + nf * 16 + l15] = f2bf(sf[nf][r]);
    __syncthreads();
    __builtin_amdgcn_s_setprio(1);
#pragma unroll
    for (int kc = 0; kc < 2; ++kc) {
      const u16* pb = &Ps[w][0] + l15 * 68 + kc * 32 + l4 * 8;
      union { u16x4 q[2]; bf16x8 v; } pu;
      pu.q[0] = *(const u16x4*)pb;
      pu.q[1] = *(const u16x4*)(pb + 4);
#pragma unroll
      for (int nf = 0; nf < 8; ++nf) {
        const int dd = nf * 16 + l15;
        const u16* vp = &Vt[0] + dd * 66 + kc * 32 + l4 * 8;
        union { u32 u[4]; bf16x8 v; } vu;
        vu.u[0] = *(const u32*)(vp);
        vu.u[1] = *(const u32*)(vp + 2);
        vu.u[2] = *(const u32*)(vp + 4);
        vu.u[3] = *(const u32*)(vp + 6);
        accO[nf] = __builtin_amdgcn_mfma_f32_16x16x32_bf16(pu.v, vu.v, accO[nf], 0, 0, 0);
      }
    }
    __builtin_amdgcn_s_setprio(0);
  }
  const int qg0 = qt * 64 + w * 16 + l4 * 4;
#pragma unroll
  for (int nf = 0; nf < 8; ++nf) {
    const int dd = nf * 16 + l15;
#pragma unroll
    for (int r = 0; r < 4; ++r) {
      const float o = accO[nf][r] / l_run[r];
      O[((size_t)(b * 1024 + qg0 + r)) * 2048 + h * 128 + dd] = f2bf(o);
    }
  }
}

// ---------------- Fused residual+rmsnorm+router + fused wsd transpose (tail blocks) ----
__global__ __launch_bounds__(256) void fuserouter_k(
    const float* __restrict__ x, const float* __restrict__ parts,
    const float* __restrict__ wn, const float* __restrict__ rw,
    float* __restrict__ X2, u16* __restrict__ HN,
    int* __restrict__ topi2, float* __restrict__ topw2, float* __restrict__ probs,
    const float* __restrict__ wsdsrc, u16* __restrict__ wtsd) {
  __shared__ u16 tile[64 * 80];
  __shared__ float red[4];
  __shared__ float racc[32];
  const int t = threadIdx.x, w = t >> 6;
  if ((int)blockIdx.x >= TT) {
    const int bi = blockIdx.x - TT;   // 344 blocks x 16 tiles = 5504
#pragma unroll 1
    for (int i = 0; i < 16; ++i) {
      const int ti = bi * 16 + i;
      ttile(wsdsrc, wtsd, FSH, 2048, (ti & 31) * 64, (ti >> 5) * 64, tile, t);
      __syncthreads();
    }
    return;
  }
  const int tok = blockIdx.x;
  const size_t base = (size_t)tok * DD + t * 8;
  float v[8];
  {
    float4 a = *(const float4*)(x + base);
    float4 b = *(const float4*)(x + base + 4);
    v[0] = a.x; v[1] = a.y; v[2] = a.z; v[3] = a.w;
    v[4] = b.x; v[5] = b.y; v[6] = b.z; v[7] = b.w;
  }
#pragma unroll
  for (int p = 0; p < 4; ++p) {
    const float* pr = parts + (size_t)p * (TT * DD) + base;
    float4 a = *(const float4*)(pr);
    float4 b = *(const float4*)(pr + 4);
    v[0] += a.x; v[1] += a.y; v[2] += a.z; v[3] += a.w;
    v[4] += b.x; v[5] += b.y; v[6] += b.z; v[7] += b.w;
  }
  *(float4*)(X2 + base) = make_float4(v[0], v[1], v[2], v[3]);
  *(float4*)(X2 + base + 4) = make_float4(v[4], v[5], v[6], v[7]);
  float ss = 0.f;
#pragma unroll
  for (int j = 0; j < 8; ++j) ss += v[j] * v[j];
#pragma unroll
  for (int m = 1; m < 64; m <<= 1) ss += __shfl_xor(ss, m);
  if ((t & 63) == 0) red[w] = ss;
  __syncthreads();
  const float sc = rsqrtf((red[0] + red[1] + red[2] + red[3]) * (1.f / DD) + 1e-6f);
  float hn[8];
  u16x8 o;
#pragma unroll
  for (int j = 0; j < 8; ++j) {
    hn[j] = v[j] * sc * wn[t * 8 + j];
    o[j] = f2bf(hn[j]);
  }
  *(u16x8*)(HN + base) = o;
  float acc[8] = {};
#pragma unroll
  for (int j = 0; j < 8; ++j) {
    const int d = t * 8 + j;
    float4 r0 = *(const float4*)(rw + d * 8);
    float4 r1 = *(const float4*)(rw + d * 8 + 4);
    acc[0] += hn[j] * r0.x; acc[1] += hn[j] * r0.y; acc[2] += hn[j] * r0.z; acc[3] += hn[j] * r0.w;
    acc[4] += hn[j] * r1.x; acc[5] += hn[j] * r1.y; acc[6] += hn[j] * r1.z; acc[7] += hn[j] * r1.w;
  }
#pragma unroll
  for (int m = 1; m < 64; m <<= 1)
#pragma unroll
    for (int e = 0; e < 8; ++e) acc[e] += __shfl_xor(acc[e], m);
  if ((t & 63) == 0)
#pragma unroll
    for (int e = 0; e < 8; ++e) racc[w * 8 + e] = acc[e];
  __syncthreads();
  if (t == 0) {
    float lg[8];
#pragma unroll
    for (int e = 0; e < 8; ++e) lg[e] = racc[e] + racc[8 + e] + racc[16 + e] + racc[24 + e];
    float mx = lg[0];
#pragma unroll
    for (int e = 1; e < 8; ++e) mx = fmaxf(mx, lg[e]);
    float p[8], sum = 0.f;
#pragma unroll
    for (int e = 0; e < 8; ++e) { p[e] = __expf(lg[e] - mx); sum += p[e]; }
    const float inv = 1.f / sum;
#pragma unroll
    for (int e = 0; e < 8; ++e) p[e] *= inv;
    *(float4*)(probs + tok * 8) = make_float4(p[0], p[1], p[2], p[3]);
    *(float4*)(probs + tok * 8 + 4) = make_float4(p[4], p[5], p[6], p[7]);
    int e0 = 0; float v0 = p[0];
#pragma unroll
    for (int e = 1; e < 8; ++e) if (p[e] > v0) { v0 = p[e]; e0 = e; }
    int e1 = (e0 == 0) ? 1 : 0; float v1 = p[e1];
#pragma unroll
    for (int e = 0; e < 8; ++e) if (e != e0 && p[e] > v1) { v1 = p[e]; e1 = e; }
    const float wsum = v0 + v1;
    topi2[tok * 2] = e0; topi2[tok * 2 + 1] = e1;
    topw2[tok * 2] = v0 / wsum; topw2[tok * 2 + 1] = v1 / wsum;
  }
}

__global__ __launch_bounds__(256) void zero_k(int* __restrict__ slot_tok,
                                              float* __restrict__ slot_w) {
  const int i = blockIdx.x * 256 + threadIdx.x;
  if (i < 6144) { slot_tok[i] = 0; slot_w[i] = 0.f; }
}

// ---------------- scan2: counts+pmean reduction + 256-row tile table ----------------
__global__ __launch_bounds__(256) void scan2_k(const int* __restrict__ topi2,
                                               const float* __restrict__ probs,
                                               int* __restrict__ cursors,
                                               int* __restrict__ tiletab,
                                               float* __restrict__ auxout) {
  const int t = threadIdx.x, w = t >> 6, l = t & 63;
  __shared__ int cnt[8];
  __shared__ float wsum[4][8];
  if (t < 8) cnt[t] = 0;
  __syncthreads();
  float ps[8] = {};
  for (int i = t; i < 2048; i += 256) {
    atomicAdd(&cnt[topi2[i * 2]], 1);
    atomicAdd(&cnt[topi2[i * 2 + 1]], 1);
    float4 a = *(const float4*)(probs + i * 8);
    float4 b = *(const float4*)(probs + i * 8 + 4);
    ps[0] += a.x; ps[1] += a.y; ps[2] += a.z; ps[3] += a.w;
    ps[4] += b.x; ps[5] += b.y; ps[6] += b.z; ps[7] += b.w;
  }
#pragma unroll
  for (int m = 1; m < 64; m <<= 1)
#pragma unroll
    for (int e = 0; e < 8; ++e) ps[e] += __shfl_xor(ps[e], m);
  if (l == 0)
#pragma unroll
    for (int e = 0; e < 8; ++e) wsum[w][e] = ps[e];
  __syncthreads();
  if (t == 0) {
    int off = 0, nt = 0;
    float aux = 0.f;
    for (int e = 0; e < 8; ++e) {
      cursors[e] = off;
      const int c = cnt[e];
      const int nte = (c + 255) >> 8;
      for (int i = 0; i < nte; ++i) {
        tiletab[1 + nt * 2] = e;
        tiletab[2 + nt * 2] = off + i * 256;
        ++nt;
      }
      off += nte * 256;
      const float pm = (wsum[0][e] + wsum[1][e] + wsum[2][e] + wsum[3][e]) * (1.f / 2048.f);
      aux += ((float)c * (1.f / 4096.f)) * pm;
    }
    tiletab[0] = nt;
    *auxout = 8.f * aux;
  }
}

// ---------------- assign: LDS-local rank, 8 global atomics per block ----------------
__global__ __launch_bounds__(256) void assign_k(const int* __restrict__ topi2,
                                                const float* __restrict__ topw2,
                                                int* __restrict__ cursors,
                                                int* __restrict__ slot_tok,
                                                float* __restrict__ slot_w,
                                                int* __restrict__ tok_slot) {
  __shared__ int lcnt[8];
  __shared__ int base[8];
  const int t = threadIdx.x;
  const int tok = blockIdx.x * 256 + t;
  if (t < 8) lcnt[t] = 0;
  __syncthreads();
  int e[2], lr[2];
#pragma unroll
  for (int j = 0; j < 2; ++j) {
    e[j] = topi2[tok * 2 + j];
    lr[j] = atomicAdd(&lcnt[e[j]], 1);
  }
  __syncthreads();
  if (t < 8) base[t] = atomicAdd(&cursors[t], lcnt[t]);
  __syncthreads();
#pragma unroll
  for (int j = 0; j < 2; ++j) {
    const int s = base[e[j]] + lr[j];
    slot_tok[s] = tok;
    slot_w[s] = topw2[tok * 2 + j];
    tok_slot[tok * 2 + j] = s;
  }
}

// ---------------- final: out += routed[s0] + routed[s1] ----------------
__global__ __launch_bounds__(256) void final_k(float* __restrict__ out,
                                               const u16* __restrict__ routed,
                                               const int* __restrict__ tok_slot) {
  const int tok = blockIdx.x, t = threadIdx.x;
  const int s0 = tok_slot[tok * 2], s1 = tok_slot[tok * 2 + 1];
  u16x8 a = ((const u16x8*)(routed + (size_t)s0 * DD))[t];
  u16x8 b = ((const u16x8*)(routed + (size_t)s1 * DD))[t];
  float* o = out + (size_t)tok * DD + t * 8;
  float4 o0 = *(const float4*)o;
  float4 o1 = *(const float4*)(o + 4);
  o0.x += bf2f(a[0]) + bf2f(b[0]); o0.y += bf2f(a[1]) + bf2f(b[1]);
  o0.z += bf2f(a[2]) + bf2f(b[2]); o0.w += bf2f(a[3]) + bf2f(b[3]);
  o1.x += bf2f(a[4]) + bf2f(b[4]); o1.y += bf2f(a[5]) + bf2f(b[5]);
  o1.z += bf2f(a[6]) + bf2f(b[6]); o1.w += bf2f(a[7]) + bf2f(b[7]);
  *(float4*)o = o0;
  *(float4*)(o + 4) = o1;
}

extern "C" void kernel_launch(void* const* d_in, const int* in_sizes, int n_in,
                              void* d_out, int out_size, void* d_ws, size_t ws_size,
                              hipStream_t stream) {
  (void)in_sizes; (void)n_in; (void)out_size; (void)ws_size;
  const float* x    = (const float*)d_in[0];
  const float* rc   = (const float*)d_in[1];
  const float* rs   = (const float*)d_in[2];
  const float* anw  = (const float*)d_in[3];
  const float* fnw  = (const float*)d_in[4];
  const float* wq   = (const float*)d_in[5];
  const float* bq   = (const float*)d_in[6];
  const float* wk   = (const float*)d_in[7];
  const float* bk   = (const float*)d_in[8];
  const float* wv   = (const float*)d_in[9];
  const float* bv   = (const float*)d_in[10];
  const float* wo   = (const float*)d_in[11];
  const float* rw   = (const float*)d_in[12];
  const float* wg   = (const float*)d_in[13];
  const float* wu   = (const float*)d_in[14];
  const float* wd   = (const float*)d_in[15];
  const float* wsg  = (const float*)d_in[16];
  const float* wsu  = (const float*)d_in[17];
  const float* wsd  = (const float*)d_in[18];

  // Workspace ~733 MB; dedicated regions, no aliasing.
  const size_t MB = (size_t)1 << 20;
  char* ws = (char*)d_ws;
  float* X2     = (float*)(ws + 0);          // 16
  u16*   HN     = (u16*)(ws + 16 * MB);      // 8
  char*  SM     = ws + 24 * MB;              // 1
  u16*   H      = (u16*)(ws + 25 * MB);      // 8
  u16*   WTQ    = (u16*)(ws + 33 * MB);      // 12
  u16*   PARTSQ = (u16*)(ws + 46 * MB);      // 26
  u16*   QR     = (u16*)(ws + 72 * MB);      // 8
  u16*   KR     = (u16*)(ws + 80 * MB);      // 2
  u16*   VBb    = (u16*)(ws + 82 * MB);      // 2
  u16*   ATTNO  = (u16*)(ws + 84 * MB);      // 8
  u16*   WTO    = (u16*)(ws + 92 * MB);      // 8
  float* PARTSW = (float*)(ws + 100 * MB);   // 64
  u16*   WTSg   = (u16*)(ws + 164 * MB);     // 44
  u16*   WTSu   = (u16*)(ws + 208 * MB);     // 44
  u16*   G      = (u16*)(ws + 252 * MB);     // 44
  u16*   WTSd   = (u16*)(ws + 296 * MB);     // 44
  u16*   PARTSD = (u16*)(ws + 340 * MB);     // 32
  u16*   WTEg   = (u16*)(ws + 372 * MB);     // 64
  u16*   WTEu   = (u16*)(ws + 436 * MB);     // 64
  u16*   WTEd   = (u16*)(ws + 500 * MB);     // 64
  u16*   ACT    = (u16*)(ws + 564 * MB);     // 24
  u16*   ROUTED = (u16*)(ws + 588 * MB);     // 24  (end 612 MB)

  int*   CURS  = (int*)(SM + 256);
  int*   TILT  = (int*)(SM + 512);
  int*   TOPI  = (int*)(SM + 4096);
  float* TOPW  = (float*)(SM + 40960);
  int*   STOK  = (int*)(SM + 73728);
  float* SW    = (float*)(SM + 98304);
  int*   TSLOT = (int*)(SM + 131072);
  float* PROBS = (float*)(SM + 163840);

  float* out  = (float*)d_out;
  float* NK   = out + 4194304;
  float* NV   = out + 2 * 4194304;
  float* AUXO = out + 3 * 4194304;

  const dim3 b256(256);
  const dim3 b512(512);

  // P1: attn rmsnorm + QKV projection (gemm8 split-K x2, bf16 parts)
  rmsnorm_k<<<TT, b256, 0, stream>>>(x, anw, H);
  transp_k<<<dim3(32, 32, 1), b256, 0, stream>>>(wq, WTQ, 2048, 2048);
  transp_k<<<dim3(8, 32, 1), b256, 0, stream>>>(wk, WTQ + (size_t)2048 * 2048, 2048, 512);
  transp_k<<<dim3(8, 32, 1), b256, 0, stream>>>(wv, WTQ + (size_t)2560 * 2048, 2048, 512);
  gemm8<10, true, false><<<dim3(12, 8, 2), b512, 0, stream>>>(
      H, WTQ, PARTSQ, nullptr, nullptr, nullptr, TT, 3072, 2048, 1024);
  // P2: rope + attention (attn hosts fused wd transpose on z==2 plane)
  rope_k<<<dim3(1024, 2), b256, 0, stream>>>(PARTSQ, PARTSQ + (size_t)TT * 3072, rc, rs,
                                             bq, bk, bv, QR, KR, VBb, NK, NV);
  attn_k<<<dim3(16, 16, 3), b256, 0, stream>>>(QR, KR, VBb, ATTNO, wd, WTEd);
  // P3: wo projection (gemm8 split-K x4, f32 parts)
  transp_k<<<dim3(32, 32, 1), b256, 0, stream>>>(wo, WTO, 2048, 2048);
  gemm8<11, true, false><<<dim3(8, 8, 4), b512, 0, stream>>>(
      ATTNO, WTO, PARTSW, nullptr, nullptr, nullptr, TT, 2048, 2048, 512);
  // P4: fused residual+rmsnorm+router (tail blocks transpose wsd); scan; assign
  zero_k<<<24, b256, 0, stream>>>(STOK, SW);
  fuserouter_k<<<TT + 344, b256, 0, stream>>>(x, PARTSW, fnw, rw, X2, HN, TOPI, TOPW, PROBS,
                                              wsd, WTSd);
  scan2_k<<<1, b256, 0, stream>>>(TOPI, PROBS, CURS, TILT, AUXO);
  assign_k<<<8, b256, 0, stream>>>(TOPI, TOPW, CURS, STOK, SW, TSLOT);
  // P5: shared expert — single fused gate+up over all 11008 cols, then down (split-K x4)
  transp_k<<<dim3(172, 32, 1), b256, 0, stream>>>(wsg, WTSg, 2048, FSH);
  transp_k<<<dim3(172, 32, 1), b256, 0, stream>>>(wsu, WTSu, 2048, FSH);
  gemm_gu<false><<<dim3(86, 8, 1), b512, 0, stream>>>(
      HN, WTSg, WTSu, G, nullptr, nullptr, 2048, FSH);
  gemm8<10, true, false><<<dim3(8, 8, 4), b512, 0, stream>>>(
      G, WTSd, PARTSD, nullptr, nullptr, nullptr, TT, 2048, FSH, 2816);
  redbf_k<<<2048, b256, 0, stream>>>(out, X2, PARTSD);
  // P6: routed experts — single fused gate+up over all 8 experts, then down
  transp_k<<<dim3(32, 32, 8), b256, 0, stream>>>(wg, WTEg, 2048, 2048);
  transp_k<<<dim3(32, 32, 8), b256, 0, stream>>>(wu, WTEu, 2048, 2048);
  gemm_gu<true><<<dim3(16, 24, 1), b512, 0, stream>>>(
      HN, WTEg, WTEu, ACT, STOK, TILT, 2048, 2048);
  gemm8<4, false, true><<<dim3(8, 24, 1), b512, 0, stream>>>(
      ACT, WTEd, ROUTED, nullptr, SW, TILT, 0, 2048, 2048, 0);
  // P7: out += routed
  final_k<<<TT, b256, 0, stream>>>(out, ROUTED, TSLOT);
}